// Round 15
// baseline (439.515 us; speedup 1.0000x reference)
//
#include <hip/hip_runtime.h>

#define S_LEN 2048
#define DINNER 512
#define NCHUNK 64
#define CLEN 32

typedef unsigned short u16;
typedef short bf16x8 __attribute__((ext_vector_type(8)));
typedef unsigned short u16x8 __attribute__((ext_vector_type(8)));  // 16 bytes
typedef float f32x4 __attribute__((ext_vector_type(4)));

__device__ __forceinline__ float bf2f(u16 u) {
  unsigned int x = ((unsigned int)u) << 16;
  float f; __builtin_memcpy(&f, &x, 4); return f;
}
__device__ __forceinline__ u16 f2bf(float f) {
  unsigned int x; __builtin_memcpy(&x, &f, 4);
  return (u16)((x + 0x7FFFu + ((x >> 16) & 1u)) >> 16);
}
__device__ __forceinline__ float ldw(const void* p, size_t i, int isbf) {
  return isbf ? bf2f(((const u16*)p)[i]) : ((const float*)p)[i];
}
__device__ __forceinline__ float siluf(float x) { return x / (1.f + __expf(-x)); }
__device__ __forceinline__ float softplusf(float x) {
  if (x > 20.f) return x;
  return log1pf(__expf(x));
}

// Detect input dtype (bf16 vs f32) from exponent-byte statistics.
__global__ __launch_bounds__(256) void detect_kernel(const void* __restrict__ x,
                                                     int* __restrict__ flag) {
  __shared__ int cnt;
  if (threadIdx.x == 0) cnt = 0;
  __syncthreads();
  u16 u = ((const u16*)x)[2 * threadIdx.x];
  int e = (u >> 7) & 0xFF;
  if (e >= 0x60 && e <= 0x8F) atomicAdd(&cnt, 1);
  __syncthreads();
  if (threadIdx.x == 0) *flag = (cnt > 128) ? 1 : 0;
}

// Precompute Acp[i][d][n] = -exp(A_log[i][d][n]) (f32, 4*512*16).
__global__ __launch_bounds__(256) void apack_kernel(
    const void* __restrict__ A_log, const int* __restrict__ pf, float* __restrict__ Acp)
{
  const int isbf = *pf;
  int idx = blockIdx.x * 256 + threadIdx.x;  // 32768
  Acp[idx] = -__expf(ldw(A_log, (size_t)idx, isbf));
}

// ---------------- weight pre-pack into MFMA fragment order ----------------
// Packed W[K][N]: chunk c = nblk16*(K/32) + kblk32, 512 bf16 per chunk;
// inside: q*128 + (n&15)*8 + (k&7).
__global__ __launch_bounds__(256) void wpack_kernel(
    const void* __restrict__ src, const int* __restrict__ pf,
    u16* __restrict__ dst, int K, int N)
{
  const int isbf = *pf;
  __shared__ float tile[32][65];
  int nb64 = blockIdx.x, kb = blockIdx.y, mat = blockIdx.z;
  size_t so = (size_t)mat * K * N;
  int tid = threadIdx.x;
  int kk = tid >> 3, nseg = (tid & 7) * 8;
#pragma unroll
  for (int j = 0; j < 8; ++j)
    tile[kk][nseg + j] = ldw(src, so + (size_t)(kb * 32 + kk) * N + nb64 * 64 + nseg + j, isbf);
  __syncthreads();
  int cc = tid >> 6, i0 = (tid & 63) * 8;
  int q = i0 >> 7, nn = (i0 >> 3) & 15;
  u16 outv[8];
#pragma unroll
  for (int j = 0; j < 8; ++j) outv[j] = f2bf(tile[q * 8 + j][cc * 16 + nn]);
  size_t doff = (size_t)mat * K * N + ((size_t)(nb64 * 4 + cc) * (K >> 5) + kb) * 512 + i0;
  *(u16x8*)(dst + doff) = *(const u16x8*)outv;
}

// Combined weight: [512 x 576] = [ xd_w@dtp_w (512) | xB_w (16) | xC_w (16) | 0 (32) ]
// packed to MFMA frag order. Grid (9 nb64, 16 kb, 4 mat).
__global__ __launch_bounds__(256) void wpack_cmb_kernel(
    const void* __restrict__ xdw, const void* __restrict__ dtpw,
    const void* __restrict__ xBw, const void* __restrict__ xCw,
    const int* __restrict__ pf, u16* __restrict__ dst)
{
  const int isbf = *pf;
  __shared__ float tile[32][65];
  int nb64 = blockIdx.x, kb = blockIdx.y, mat = blockIdx.z;
  int tid = threadIdx.x;
  if (nb64 < 8) {
    __shared__ float xd[32][33];
    __shared__ float wt[32][65];
    {
      int k = tid >> 3, j0 = (tid & 7) * 4;
#pragma unroll
      for (int j = 0; j < 4; ++j)
        xd[k][j0 + j] = ldw(xdw, (size_t)mat * 16384 + (size_t)(kb * 32 + k) * 32 + j0 + j, isbf);
      int jj = tid >> 3, n0l = (tid & 7) * 8;
#pragma unroll
      for (int n = 0; n < 8; ++n)
        wt[jj][n0l + n] = ldw(dtpw, (size_t)mat * 16384 + (size_t)jj * 512 + nb64 * 64 + n0l + n, isbf);
    }
    __syncthreads();
    for (int l = tid; l < 2048; l += 256) {
      int k = l >> 6, n = l & 63;
      float a = 0.f;
#pragma unroll
      for (int j = 0; j < 32; ++j) a += xd[k][j] * wt[j][n];
      tile[k][n] = a;
    }
  } else {
    for (int l = tid; l < 2048; l += 256) {
      int k = l >> 6, n = l & 63;
      int kg = kb * 32 + k;
      float v = 0.f;
      if (n < 16)      v = ldw(xBw, (size_t)mat * 8192 + (size_t)kg * 16 + n, isbf);
      else if (n < 32) v = ldw(xCw, (size_t)mat * 8192 + (size_t)kg * 16 + (n - 16), isbf);
      tile[k][n] = v;
    }
  }
  __syncthreads();
  int cc = tid >> 6, i0 = (tid & 63) * 8;
  int q = i0 >> 7, nn = (i0 >> 3) & 15;
  u16 outv[8];
#pragma unroll
  for (int j = 0; j < 8; ++j) outv[j] = f2bf(tile[q * 8 + j][cc * 16 + nn]);
  size_t doff = (size_t)mat * 294912 + ((size_t)(nb64 * 4 + cc) * 16 + kb) * 512 + i0;
  *(u16x8*)(dst + doff) = *(const u16x8*)outv;
}

// ---------------- LayerNorm (batched 2 chains) ----------------
__global__ __launch_bounds__(256) void ln_kernel(
    const void* __restrict__ x, const u16* __restrict__ obA, int it,
    const void* __restrict__ g, const void* __restrict__ bta,
    const int* __restrict__ pf, float* __restrict__ res, u16* __restrict__ xnb)
{
  const int isbf = *pf;
  int r = blockIdx.x;
  int tid = threadIdx.x;
  int chain = r >> 12, rr = r & 4095;
  int i = chain * 2 + it;
  size_t wo = (size_t)i * 256;
  float v;
  if (it == 0) {
    int b = rr >> 11, s = rr & 2047;
    int sr = chain ? (b * S_LEN + (S_LEN - 1 - s)) : rr;
    v = ldw(x, (size_t)sr * 256 + tid, isbf);
  } else {
    v = bf2f(obA[(size_t)r * 256 + tid]);
  }
  res[(size_t)r * 256 + tid] = v;
  float s1 = v, s2 = v * v;
#pragma unroll
  for (int o = 32; o > 0; o >>= 1) {
    s1 += __shfl_xor(s1, o, 64);
    s2 += __shfl_xor(s2, o, 64);
  }
  __shared__ float r1[4], r2[4];
  if ((tid & 63) == 0) { r1[tid >> 6] = s1; r2[tid >> 6] = s2; }
  __syncthreads();
  s1 = r1[0] + r1[1] + r1[2] + r1[3];
  s2 = r2[0] + r2[1] + r2[2] + r2[3];
  float mean = s1 * (1.f / 256.f);
  float var  = s2 * (1.f / 256.f) - mean * mean;
  float inv  = rsqrtf(var + 1e-5f);
  xnb[(size_t)r * 256 + tid] =
      f2bf((v - mean) * inv * ldw(g, wo + tid, isbf) + ldw(bta, wo + tid, isbf));
}

// ---------------- 4-wave MFMA GEMM: 64x64 tile, LDS-staged A and B ----------------
// 256 threads = 4 waves, 2x2 over the tile; each wave 32x32 (4 MFMA/K-step).
// OUTMODE 1: final dtype per flag. 2: bf16 [+res]. 3: cat buffer [+res].
// 5: cols<512 -> softplus(v+bias)->bf16 Out; cols 512-543 -> f32 Out2 (stride 32).
template<int OUTMODE>
__global__ __launch_bounds__(256) void gemm64(
    const u16* __restrict__ A, const u16* __restrict__ Wp, size_t woA, size_t woB, int mhalf,
    const float* __restrict__ res, void* __restrict__ Out, void* __restrict__ Out2,
    const void* __restrict__ bias, size_t boA, size_t boB,
    const int* __restrict__ pf, int N, int K)
{
  const int isbf = *pf;
  __shared__ __align__(16) u16 Asb[64 * 32];
  __shared__ __align__(16) u16 Bsb[64 * 32];
  int tid = threadIdx.x;
  int n0 = blockIdx.x * 64, m0 = blockIdx.y * 64;
  size_t wo = (mhalf && m0 >= mhalf) ? woB : woA;
  int w = tid >> 6, lane = tid & 63;
  int q = lane >> 4, r = lane & 15;
  const int wm0 = (w >> 1) * 2, wn0 = (w & 1) * 2;
  const int kbs = K >> 5;
  f32x4 acc[2][2];
#pragma unroll
  for (int i = 0; i < 2; ++i)
#pragma unroll
    for (int j = 0; j < 2; ++j) acc[i][j] = (f32x4){0.f, 0.f, 0.f, 0.f};

  int sm = tid >> 2, sq = tid & 3;
  const u16* asrc = A + (size_t)(m0 + sm) * K + sq * 8;
  u16* adst = Asb + ((sm >> 4) * 4 + sq) * 128 + (sm & 15) * 8;
  int bnb = tid >> 6, binner = (tid & 63) * 8;
  u16* bdst = Bsb + bnb * 512 + binner;

  for (int k0 = 0; k0 < K; k0 += 32) {
    *(u16x8*)adst = *(const u16x8*)(asrc + k0);
    const u16* bsrc = Wp + wo + ((size_t)((n0 >> 4) + bnb) * kbs + (k0 >> 5)) * 512 + binner;
    *(u16x8*)bdst = *(const u16x8*)bsrc;
    __syncthreads();
    bf16x8 af[2], bfr[2];
#pragma unroll
    for (int i = 0; i < 2; ++i)
      af[i] = *(const bf16x8*)(Asb + ((wm0 + i) * 4 + q) * 128 + r * 8);
#pragma unroll
    for (int j = 0; j < 2; ++j)
      bfr[j] = *(const bf16x8*)(Bsb + ((wn0 + j) * 4 + q) * 128 + r * 8);
#pragma unroll
    for (int i = 0; i < 2; ++i)
#pragma unroll
      for (int j = 0; j < 2; ++j)
        acc[i][j] = __builtin_amdgcn_mfma_f32_16x16x32_bf16(af[i], bfr[j], acc[i][j], 0, 0, 0);
    __syncthreads();
  }
#pragma unroll
  for (int i = 0; i < 2; ++i) {
    int rowb = m0 + (wm0 + i) * 16 + q * 4;
#pragma unroll
    for (int j = 0; j < 2; ++j) {
      int col = n0 + (wn0 + j) * 16 + r;
#pragma unroll
      for (int t = 0; t < 4; ++t) {
        int row = rowb + t;
        float v = acc[i][j][t];
        if (OUTMODE == 2 || OUTMODE == 3) { if (res) v += res[(size_t)row * N + col]; }
        if (OUTMODE == 1) {
          size_t lidx = (size_t)row * N + col;
          if (isbf) ((u16*)Out)[lidx] = f2bf(v); else ((float*)Out)[lidx] = v;
        } else if (OUTMODE == 2) {
          ((u16*)Out)[(size_t)row * N + col] = f2bf(v);
        } else if (OUTMODE == 3) {
          int orow, cofx;
          if (row < 4096) { orow = row; cofx = 0; }
          else {
            int rr = row - 4096; int bb = rr >> 11, ss = rr & 2047;
            orow = bb * S_LEN + (S_LEN - 1 - ss); cofx = 256;
          }
          ((u16*)Out)[(size_t)orow * 512 + col + cofx] = f2bf(v);
        } else if (OUTMODE == 5) {
          if (col < 512) {
            float bv = ldw(bias, ((row < 4096) ? boA : boB) + col, isbf);
            ((u16*)Out)[(size_t)row * 512 + col] = f2bf(softplusf(v + bv));
          } else if (col < 544) {
            ((float*)Out2)[(size_t)row * 32 + (col - 512)] = v;
          }
        }
      }
    }
  }
}

// ---------------- vectorized causal depthwise conv: 8 d per thread ----------------
__global__ __launch_bounds__(256) void conv_kernel(
    const u16* __restrict__ xzb, const void* __restrict__ cw, const void* __restrict__ cb,
    int it, const int* __restrict__ pf, u16* __restrict__ xcb)
{
  const int isbf = *pf;
  int g = blockIdx.x * 256 + threadIdx.x;   // 8192 * 64 groups
  int r = g >> 6, d0 = (g & 63) * 8;
  int chain = r >> 12, rr = r & 4095;
  int i = chain * 2 + it;
  size_t ow = (size_t)i * 2048, ob = (size_t)i * 512;
  int s = rr & 2047;
  float acc[8];
#pragma unroll
  for (int j = 0; j < 8; ++j) acc[j] = ldw(cb, ob + d0 + j, isbf);
#pragma unroll
  for (int k = 0; k < 4; ++k) {
    int t = s - 3 + k;
    if (t >= 0) {
      u16x8 xv = *(const u16x8*)(xzb + ((size_t)(r + t - s) << 10) + d0);
#pragma unroll
      for (int j = 0; j < 8; ++j)
        acc[j] += ldw(cw, ow + (size_t)(d0 + j) * 4 + k, isbf) * bf2f(xv[j]);
    }
  }
  u16 outv[8];
#pragma unroll
  for (int j = 0; j < 8; ++j) outv[j] = f2bf(siluf(acc[j]));
  *(u16x8*)(xcb + (size_t)r * 512 + d0) = *(const u16x8*)outv;
}

// ---------------- 3-phase scan: 4 n-states/thread; dBC is [rows][32] = B|C ----------
__global__ __launch_bounds__(256) void scan_p1_kernel(
    const u16* __restrict__ xcb, const u16* __restrict__ delb, const float* __restrict__ dBC,
    const float* __restrict__ Acp, int it, const int* __restrict__ pf,
    float* __restrict__ aggA, float* __restrict__ aggB)
{
  __shared__ float sb[32][16];   // B
  __shared__ u16 sdu[32][64];
  __shared__ u16 sxu[32][64];
  int tid = threadIdx.x;
  int di = tid >> 2, ng = tid & 3;
  int d0 = blockIdx.x << 6;
  int c = blockIdx.y, seq = blockIdx.z;
  int chain = seq >> 1, bb = seq & 1;
  int row0 = chain * 4096 + bb * S_LEN + c * CLEN;
  int i = chain * 2 + it;
  {
    int t = tid >> 3, e0 = (tid & 7) * 8;
    *(u16x8*)&sdu[t][e0] = *(const u16x8*)(delb + (size_t)(row0 + t) * 512 + d0 + e0);
    *(u16x8*)&sxu[t][e0] = *(const u16x8*)(xcb + (size_t)(row0 + t) * 512 + d0 + e0);
  }
  if (tid < 128) {
    int t = tid >> 2, e0 = (tid & 3) * 4;
    *(f32x4*)&sb[t][e0] = *(const f32x4*)(dBC + (size_t)(row0 + t) * 32 + e0);
  }
  f32x4 Ac = *(const f32x4*)(Acp + ((size_t)i * 512 + d0 + di) * 16 + ng * 4);
  __syncthreads();
  float h[4] = {0.f, 0.f, 0.f, 0.f};
  float ap[4] = {1.f, 1.f, 1.f, 1.f};
#pragma unroll 8
  for (int t = 0; t < CLEN; ++t) {
    float de = bf2f(sdu[t][di]);
    float dx = de * bf2f(sxu[t][di]);
    f32x4 B = *(const f32x4*)&sb[t][ng * 4];
#pragma unroll
    for (int j = 0; j < 4; ++j) {
      float e = __expf(de * Ac[j]);
      h[j] = e * h[j] + dx * B[j];
      ap[j] *= e;
    }
  }
  size_t o = (((size_t)(seq * NCHUNK + c) * DINNER) + d0 + di) * 16 + ng * 4;
  *(f32x4*)(aggA + o) = (f32x4){ap[0], ap[1], ap[2], ap[3]};
  *(f32x4*)(aggB + o) = (f32x4){h[0], h[1], h[2], h[3]};
}

__global__ __launch_bounds__(256) void scan_prefix_kernel(
    const float* __restrict__ aggA, float* __restrict__ aggB)
{
  int idx = blockIdx.x * 256 + threadIdx.x;   // 4*512*16
  int n = idx & 15, d = (idx >> 4) & 511, seq = idx >> 13;
  float h = 0.f;
  for (int c = 0; c < NCHUNK; ++c) {
    size_t o = (((size_t)(seq * NCHUNK + c) * DINNER) + d) * 16 + n;
    float a = aggA[o], t = aggB[o];
    aggB[o] = h;
    h = a * h + t;
  }
}

__global__ __launch_bounds__(256) void scan_p3_kernel(
    const u16* __restrict__ xcb, const u16* __restrict__ delb, const float* __restrict__ dBC,
    const u16* __restrict__ xzb, const float* __restrict__ hpref,
    const float* __restrict__ Acp, const void* __restrict__ Dp,
    int it, const int* __restrict__ pf, u16* __restrict__ ymb)
{
  const int isbf = *pf;
  __shared__ float sbc[32][32];  // B | C
  __shared__ float sy[32][64];
  __shared__ u16 sdu[32][64];
  __shared__ u16 sxu[32][64];
  __shared__ u16 szu[32][64];
  int tid = threadIdx.x;
  int di = tid >> 2, ng = tid & 3;
  int d0 = blockIdx.x << 6;
  int c = blockIdx.y, seq = blockIdx.z;
  int chain = seq >> 1, bb = seq & 1;
  int row0 = chain * 4096 + bb * S_LEN + c * CLEN;
  int i = chain * 2 + it;
  size_t oD = (size_t)i * 512;
  {
    int t = tid >> 3, e0 = (tid & 7) * 8;
    *(u16x8*)&sdu[t][e0] = *(const u16x8*)(delb + (size_t)(row0 + t) * 512 + d0 + e0);
    *(u16x8*)&sxu[t][e0] = *(const u16x8*)(xcb + (size_t)(row0 + t) * 512 + d0 + e0);
    *(u16x8*)&szu[t][e0] = *(const u16x8*)(xzb + ((size_t)(row0 + t) << 10) + 512 + d0 + e0);
  }
  {
    int t = tid >> 3, e0 = (tid & 7) * 4;
    *(f32x4*)&sbc[t][e0] = *(const f32x4*)(dBC + (size_t)(row0 + t) * 32 + e0);
  }
  f32x4 Ac = *(const f32x4*)(Acp + ((size_t)i * 512 + d0 + di) * 16 + ng * 4);
  float Dv = ldw(Dp, oD + d0 + di, isbf);
  float h[4];
  size_t o = (((size_t)(seq * NCHUNK + c) * DINNER) + d0 + di) * 16 + ng * 4;
  {
    f32x4 v = *(const f32x4*)(hpref + o);
    h[0] = v[0]; h[1] = v[1]; h[2] = v[2]; h[3] = v[3];
  }
  __syncthreads();
#pragma unroll 8
  for (int t = 0; t < CLEN; ++t) {
    float de = bf2f(sdu[t][di]);
    float xv = bf2f(sxu[t][di]);
    float dx = de * xv;
    f32x4 B = *(const f32x4*)&sbc[t][ng * 4];
    f32x4 C = *(const f32x4*)&sbc[t][16 + ng * 4];
    float yc = 0.f;
#pragma unroll
    for (int j = 0; j < 4; ++j) {
      float e = __expf(de * Ac[j]);
      h[j] = e * h[j] + dx * B[j];
      yc += h[j] * C[j];
    }
    yc += __shfl_xor(yc, 1, 64);
    yc += __shfl_xor(yc, 2, 64);
    if (ng == 0) sy[t][di] = yc + Dv * xv;
  }
  __syncthreads();
  int dcol = tid & 63;
#pragma unroll
  for (int k = 0; k < 8; ++k) {
    int t = (tid >> 6) + k * 4;
    float y = sy[t][dcol];
    float z = bf2f(szu[t][dcol]);
    ymb[(size_t)(row0 + t) * 512 + d0 + dcol] = f2bf(y * siluf(z));
  }
}

extern "C" void kernel_launch(void* const* d_in, const int* in_sizes, int n_in,
                              void* d_out, int out_size, void* d_ws, size_t ws_size,
                              hipStream_t stream)
{
  const void* x       = d_in[0];
  const void* in_w    = d_in[1];
  const void* conv_w  = d_in[2];
  const void* conv_b  = d_in[3];
  const void* A_log   = d_in[4];
  const void* xd_w    = d_in[5];
  const void* xB_w    = d_in[6];
  const void* xC_w    = d_in[7];
  const void* dtp_w   = d_in[8];
  const void* dtp_b   = d_in[9];
  const void* Dp      = d_in[10];
  const void* out_w   = d_in[11];
  const void* ln_g    = d_in[12];
  const void* ln_b    = d_in[13];
  const void* merge_w = d_in[14];

  // ---- workspace (~62.6 MB; proven-safe >= 65.5 MB) ----
  float* ws    = (float*)d_ws;
  float* res   = ws;                             // 8192x256 f32
  float* dBC   = res + (size_t)8192 * 256;       // 8192x32 f32 (B|C)
  float* aggA  = dBC + (size_t)8192 * 32;        // 2M f32 (xn & ym alias)
  float* aggB  = aggA + (size_t)2097152;         // 2M f32 (-> hpref)
  u16*   xz_bf = (u16*)(aggB + (size_t)2097152); // 8192x1024 (obA alias head)
  u16*   xc_bf = xz_bf + (size_t)8192 * 1024;    // 8192x512
  u16*   del_bf= xc_bf + (size_t)8192 * 512;     // 8192x512 (cat alias head)
  u16*   Wp_in = del_bf + (size_t)8192 * 512;    // 4*256*1024
  u16*   Wp_out= Wp_in + (size_t)4 * 262144;     // 4*512*256
  u16*   Wp_mg = Wp_out + (size_t)4 * 131072;    // 512*256
  u16*   Wp_cmb= Wp_mg + (size_t)131072;         // 4*512*576
  float* Acp   = (float*)(Wp_cmb + (size_t)4 * 294912);  // 4*512*16 f32
  int*   flagp = (int*)(Acp + (size_t)4 * 8192);
  u16*   obA_bf= xz_bf;          // alias
  u16*   xn_bf = (u16*)aggA;     // alias
  u16*   ym_bf = (u16*)aggA;     // alias
  u16*   cat_bf= del_bf;         // alias

  dim3 blk(256);
  hipLaunchKernelGGL(detect_kernel, dim3(1), blk, 0, stream, x, flagp);
  hipLaunchKernelGGL(apack_kernel, dim3(128), blk, 0, stream, A_log, flagp, Acp);
  hipLaunchKernelGGL(wpack_kernel, dim3(16, 8, 4), blk, 0, stream, in_w, flagp, Wp_in, 256, 1024);
  hipLaunchKernelGGL(wpack_kernel, dim3(4, 16, 4), blk, 0, stream, out_w, flagp, Wp_out, 512, 256);
  hipLaunchKernelGGL(wpack_kernel, dim3(4, 16, 1), blk, 0, stream, merge_w, flagp, Wp_mg, 512, 256);
  hipLaunchKernelGGL(wpack_cmb_kernel, dim3(9, 16, 4), blk, 0, stream,
      xd_w, dtp_w, xB_w, xC_w, flagp, Wp_cmb);

  for (int it = 0; it < 2; ++it) {
    hipLaunchKernelGGL(ln_kernel, dim3(8192), blk, 0, stream,
        x, obA_bf, it, ln_g, ln_b, flagp, res, xn_bf);
    hipLaunchKernelGGL((gemm64<2>), dim3(16, 128), blk, 0, stream,
        xn_bf, Wp_in, (size_t)it * 262144, (size_t)(2 + it) * 262144, 4096,
        (const float*)nullptr, (void*)xz_bf, (void*)nullptr,
        (const void*)nullptr, (size_t)0, (size_t)0, flagp, 1024, 256);
    hipLaunchKernelGGL(conv_kernel, dim3(2048), blk, 0, stream,
        xz_bf, conv_w, conv_b, it, flagp, xc_bf);
    hipLaunchKernelGGL((gemm64<5>), dim3(9, 128), blk, 0, stream,
        xc_bf, Wp_cmb, (size_t)it * 294912, (size_t)(2 + it) * 294912, 4096,
        (const float*)nullptr, (void*)del_bf, (void*)dBC,
        dtp_b, (size_t)it * 512, (size_t)(2 + it) * 512, flagp, 576, 512);
    hipLaunchKernelGGL(scan_p1_kernel, dim3(8, NCHUNK, 4), blk, 0, stream,
        xc_bf, del_bf, dBC, Acp, it, flagp, aggA, aggB);
    hipLaunchKernelGGL(scan_prefix_kernel, dim3(128), blk, 0, stream, aggA, aggB);
    hipLaunchKernelGGL(scan_p3_kernel, dim3(8, NCHUNK, 4), blk, 0, stream,
        xc_bf, del_bf, dBC, xz_bf, aggB, Acp, Dp, it, flagp, ym_bf);
    if (it == 0) {
      hipLaunchKernelGGL((gemm64<2>), dim3(4, 128), blk, 0, stream,
          ym_bf, Wp_out, (size_t)0, (size_t)2 * 131072, 4096,
          res, (void*)obA_bf, (void*)nullptr,
          (const void*)nullptr, (size_t)0, (size_t)0, flagp, 256, 512);
    } else {
      hipLaunchKernelGGL((gemm64<3>), dim3(4, 128), blk, 0, stream,
          ym_bf, Wp_out, (size_t)1 * 131072, (size_t)3 * 131072, 4096,
          res, (void*)cat_bf, (void*)nullptr,
          (const void*)nullptr, (size_t)0, (size_t)0, flagp, 256, 512);
    }
  }
  hipLaunchKernelGGL((gemm64<1>), dim3(4, 64), blk, 0, stream,
      cat_bf, Wp_mg, (size_t)0, (size_t)0, 0,
      (const float*)nullptr, d_out, (void*)nullptr,
      (const void*)nullptr, (size_t)0, (size_t)0, flagp, 256, 512);
}

// Round 16
// 403.849 us; speedup vs baseline: 1.0883x; 1.0883x over previous
//
#include <hip/hip_runtime.h>

#define S_LEN 2048
#define DINNER 512
#define NCHUNK 64
#define CLEN 32

typedef unsigned short u16;
typedef short bf16x8 __attribute__((ext_vector_type(8)));
typedef unsigned short u16x8 __attribute__((ext_vector_type(8)));  // 16 bytes
typedef float f32x4 __attribute__((ext_vector_type(4)));

__device__ __forceinline__ float bf2f(u16 u) {
  unsigned int x = ((unsigned int)u) << 16;
  float f; __builtin_memcpy(&f, &x, 4); return f;
}
__device__ __forceinline__ u16 f2bf(float f) {
  unsigned int x; __builtin_memcpy(&x, &f, 4);
  return (u16)((x + 0x7FFFu + ((x >> 16) & 1u)) >> 16);
}
__device__ __forceinline__ float ldw(const void* p, size_t i, int isbf) {
  return isbf ? bf2f(((const u16*)p)[i]) : ((const float*)p)[i];
}
__device__ __forceinline__ float siluf(float x) { return x / (1.f + __expf(-x)); }
__device__ __forceinline__ float softplusf(float x) {
  if (x > 20.f) return x;
  return log1pf(__expf(x));
}

// Detect input dtype (bf16 vs f32) from exponent-byte statistics.
__global__ __launch_bounds__(256) void detect_kernel(const void* __restrict__ x,
                                                     int* __restrict__ flag) {
  __shared__ int cnt;
  if (threadIdx.x == 0) cnt = 0;
  __syncthreads();
  u16 u = ((const u16*)x)[2 * threadIdx.x];
  int e = (u >> 7) & 0xFF;
  if (e >= 0x60 && e <= 0x8F) atomicAdd(&cnt, 1);
  __syncthreads();
  if (threadIdx.x == 0) *flag = (cnt > 128) ? 1 : 0;
}

// Precompute Acp[i][d][n] = -exp(A_log[i][d][n]) (f32, 4*512*16).
__global__ __launch_bounds__(256) void apack_kernel(
    const void* __restrict__ A_log, const int* __restrict__ pf, float* __restrict__ Acp)
{
  const int isbf = *pf;
  int idx = blockIdx.x * 256 + threadIdx.x;  // 32768
  Acp[idx] = -__expf(ldw(A_log, (size_t)idx, isbf));
}

// ---------------- weight pre-pack into MFMA fragment order ----------------
// Packed W[K][N]: chunk c = nblk16*(K/32) + kblk32, 512 bf16 per chunk;
// inside: q*128 + (n&15)*8 + (k&7).
__global__ __launch_bounds__(256) void wpack_kernel(
    const void* __restrict__ src, const int* __restrict__ pf,
    u16* __restrict__ dst, int K, int N)
{
  const int isbf = *pf;
  __shared__ float tile[32][65];
  int nb64 = blockIdx.x, kb = blockIdx.y, mat = blockIdx.z;
  size_t so = (size_t)mat * K * N;
  int tid = threadIdx.x;
  int kk = tid >> 3, nseg = (tid & 7) * 8;
#pragma unroll
  for (int j = 0; j < 8; ++j)
    tile[kk][nseg + j] = ldw(src, so + (size_t)(kb * 32 + kk) * N + nb64 * 64 + nseg + j, isbf);
  __syncthreads();
  int cc = tid >> 6, i0 = (tid & 63) * 8;
  int q = i0 >> 7, nn = (i0 >> 3) & 15;
  u16 outv[8];
#pragma unroll
  for (int j = 0; j < 8; ++j) outv[j] = f2bf(tile[q * 8 + j][cc * 16 + nn]);
  size_t doff = (size_t)mat * K * N + ((size_t)(nb64 * 4 + cc) * (K >> 5) + kb) * 512 + i0;
  *(u16x8*)(dst + doff) = *(const u16x8*)outv;
}

// Combined weight: [512 x 576] = [ xd_w@dtp_w (512) | xB_w (16) | xC_w (16) | 0 (32) ]
// packed to MFMA frag order. Grid (9 nb64, 16 kb, 4 mat).
__global__ __launch_bounds__(256) void wpack_cmb_kernel(
    const void* __restrict__ xdw, const void* __restrict__ dtpw,
    const void* __restrict__ xBw, const void* __restrict__ xCw,
    const int* __restrict__ pf, u16* __restrict__ dst)
{
  const int isbf = *pf;
  __shared__ float tile[32][65];
  int nb64 = blockIdx.x, kb = blockIdx.y, mat = blockIdx.z;
  int tid = threadIdx.x;
  if (nb64 < 8) {
    __shared__ float xd[32][33];
    __shared__ float wt[32][65];
    {
      int k = tid >> 3, j0 = (tid & 7) * 4;
#pragma unroll
      for (int j = 0; j < 4; ++j)
        xd[k][j0 + j] = ldw(xdw, (size_t)mat * 16384 + (size_t)(kb * 32 + k) * 32 + j0 + j, isbf);
      int jj = tid >> 3, n0l = (tid & 7) * 8;
#pragma unroll
      for (int n = 0; n < 8; ++n)
        wt[jj][n0l + n] = ldw(dtpw, (size_t)mat * 16384 + (size_t)jj * 512 + nb64 * 64 + n0l + n, isbf);
    }
    __syncthreads();
    for (int l = tid; l < 2048; l += 256) {
      int k = l >> 6, n = l & 63;
      float a = 0.f;
#pragma unroll
      for (int j = 0; j < 32; ++j) a += xd[k][j] * wt[j][n];
      tile[k][n] = a;
    }
  } else {
    for (int l = tid; l < 2048; l += 256) {
      int k = l >> 6, n = l & 63;
      int kg = kb * 32 + k;
      float v = 0.f;
      if (n < 16)      v = ldw(xBw, (size_t)mat * 8192 + (size_t)kg * 16 + n, isbf);
      else if (n < 32) v = ldw(xCw, (size_t)mat * 8192 + (size_t)kg * 16 + (n - 16), isbf);
      tile[k][n] = v;
    }
  }
  __syncthreads();
  int cc = tid >> 6, i0 = (tid & 63) * 8;
  int q = i0 >> 7, nn = (i0 >> 3) & 15;
  u16 outv[8];
#pragma unroll
  for (int j = 0; j < 8; ++j) outv[j] = f2bf(tile[q * 8 + j][cc * 16 + nn]);
  size_t doff = (size_t)mat * 294912 + ((size_t)(nb64 * 4 + cc) * 16 + kb) * 512 + i0;
  *(u16x8*)(dst + doff) = *(const u16x8*)outv;
}

// ---------------- LayerNorm (batched 2 chains) ----------------
__global__ __launch_bounds__(256) void ln_kernel(
    const void* __restrict__ x, const u16* __restrict__ obA, int it,
    const void* __restrict__ g, const void* __restrict__ bta,
    const int* __restrict__ pf, float* __restrict__ res, u16* __restrict__ xnb)
{
  const int isbf = *pf;
  int r = blockIdx.x;
  int tid = threadIdx.x;
  int chain = r >> 12, rr = r & 4095;
  int i = chain * 2 + it;
  size_t wo = (size_t)i * 256;
  float v;
  if (it == 0) {
    int b = rr >> 11, s = rr & 2047;
    int sr = chain ? (b * S_LEN + (S_LEN - 1 - s)) : rr;
    v = ldw(x, (size_t)sr * 256 + tid, isbf);
  } else {
    v = bf2f(obA[(size_t)r * 256 + tid]);
  }
  res[(size_t)r * 256 + tid] = v;
  float s1 = v, s2 = v * v;
#pragma unroll
  for (int o = 32; o > 0; o >>= 1) {
    s1 += __shfl_xor(s1, o, 64);
    s2 += __shfl_xor(s2, o, 64);
  }
  __shared__ float r1[4], r2[4];
  if ((tid & 63) == 0) { r1[tid >> 6] = s1; r2[tid >> 6] = s2; }
  __syncthreads();
  s1 = r1[0] + r1[1] + r1[2] + r1[3];
  s2 = r2[0] + r2[1] + r2[2] + r2[3];
  float mean = s1 * (1.f / 256.f);
  float var  = s2 * (1.f / 256.f) - mean * mean;
  float inv  = rsqrtf(var + 1e-5f);
  xnb[(size_t)r * 256 + tid] =
      f2bf((v - mean) * inv * ldw(g, wo + tid, isbf) + ldw(bta, wo + tid, isbf));
}

// ---------------- 4-wave MFMA GEMM: 64x64 tile, LDS-staged A and B ----------------
// 256 threads = 4 waves, 2x2 over the tile; each wave 32x32 (4 MFMA/K-step).
// OUTMODE 1: final dtype per flag. 2: bf16 [+res]. 3: cat buffer [+res].
// 5: cols<512 -> softplus(v+bias)->bf16 Out; cols 512-543 -> f32 Out2 (stride 32).
template<int OUTMODE>
__global__ __launch_bounds__(256) void gemm64(
    const u16* __restrict__ A, const u16* __restrict__ Wp, size_t woA, size_t woB, int mhalf,
    const float* __restrict__ res, void* __restrict__ Out, void* __restrict__ Out2,
    const void* __restrict__ bias, size_t boA, size_t boB,
    const int* __restrict__ pf, int N, int K)
{
  const int isbf = *pf;
  __shared__ __align__(16) u16 Asb[64 * 32];
  __shared__ __align__(16) u16 Bsb[64 * 32];
  int tid = threadIdx.x;
  int n0 = blockIdx.x * 64, m0 = blockIdx.y * 64;
  size_t wo = (mhalf && m0 >= mhalf) ? woB : woA;
  int w = tid >> 6, lane = tid & 63;
  int q = lane >> 4, r = lane & 15;
  const int wm0 = (w >> 1) * 2, wn0 = (w & 1) * 2;
  const int kbs = K >> 5;
  f32x4 acc[2][2];
#pragma unroll
  for (int i = 0; i < 2; ++i)
#pragma unroll
    for (int j = 0; j < 2; ++j) acc[i][j] = (f32x4){0.f, 0.f, 0.f, 0.f};

  int sm = tid >> 2, sq = tid & 3;
  const u16* asrc = A + (size_t)(m0 + sm) * K + sq * 8;
  u16* adst = Asb + ((sm >> 4) * 4 + sq) * 128 + (sm & 15) * 8;
  int bnb = tid >> 6, binner = (tid & 63) * 8;
  u16* bdst = Bsb + bnb * 512 + binner;

  for (int k0 = 0; k0 < K; k0 += 32) {
    *(u16x8*)adst = *(const u16x8*)(asrc + k0);
    const u16* bsrc = Wp + wo + ((size_t)((n0 >> 4) + bnb) * kbs + (k0 >> 5)) * 512 + binner;
    *(u16x8*)bdst = *(const u16x8*)bsrc;
    __syncthreads();
    bf16x8 af[2], bfr[2];
#pragma unroll
    for (int i = 0; i < 2; ++i)
      af[i] = *(const bf16x8*)(Asb + ((wm0 + i) * 4 + q) * 128 + r * 8);
#pragma unroll
    for (int j = 0; j < 2; ++j)
      bfr[j] = *(const bf16x8*)(Bsb + ((wn0 + j) * 4 + q) * 128 + r * 8);
#pragma unroll
    for (int i = 0; i < 2; ++i)
#pragma unroll
      for (int j = 0; j < 2; ++j)
        acc[i][j] = __builtin_amdgcn_mfma_f32_16x16x32_bf16(af[i], bfr[j], acc[i][j], 0, 0, 0);
    __syncthreads();
  }
#pragma unroll
  for (int i = 0; i < 2; ++i) {
    int rowb = m0 + (wm0 + i) * 16 + q * 4;
#pragma unroll
    for (int j = 0; j < 2; ++j) {
      int col = n0 + (wn0 + j) * 16 + r;
#pragma unroll
      for (int t = 0; t < 4; ++t) {
        int row = rowb + t;
        float v = acc[i][j][t];
        if (OUTMODE == 2 || OUTMODE == 3) { if (res) v += res[(size_t)row * N + col]; }
        if (OUTMODE == 1) {
          size_t lidx = (size_t)row * N + col;
          if (isbf) ((u16*)Out)[lidx] = f2bf(v); else ((float*)Out)[lidx] = v;
        } else if (OUTMODE == 2) {
          ((u16*)Out)[(size_t)row * N + col] = f2bf(v);
        } else if (OUTMODE == 3) {
          int orow, cofx;
          if (row < 4096) { orow = row; cofx = 0; }
          else {
            int rr = row - 4096; int bb = rr >> 11, ss = rr & 2047;
            orow = bb * S_LEN + (S_LEN - 1 - ss); cofx = 256;
          }
          ((u16*)Out)[(size_t)orow * 512 + col + cofx] = f2bf(v);
        } else if (OUTMODE == 5) {
          if (col < 512) {
            float bv = ldw(bias, ((row < 4096) ? boA : boB) + col, isbf);
            ((u16*)Out)[(size_t)row * 512 + col] = f2bf(softplusf(v + bv));
          } else if (col < 544) {
            ((float*)Out2)[(size_t)row * 32 + (col - 512)] = v;
          }
        }
      }
    }
  }
}

// ---------------- causal depthwise conv K=4 + bias + SiLU, batched (R14 form) -------
__global__ __launch_bounds__(256) void conv_kernel(
    const u16* __restrict__ xzb, const void* __restrict__ cw, const void* __restrict__ cb,
    int it, const int* __restrict__ pf, u16* __restrict__ xcb)
{
  const int isbf = *pf;
  int idx = blockIdx.x * 256 + threadIdx.x;  // 8192*512
  int r = idx >> 9, d = idx & 511;
  int chain = r >> 12, rr = r & 4095;
  int i = chain * 2 + it;
  size_t ow = (size_t)i * 2048, ob = (size_t)i * 512;
  int s = rr & 2047;
  float acc = ldw(cb, ob + d, isbf);
#pragma unroll
  for (int k = 0; k < 4; ++k) {
    int t = s - 3 + k;
    if (t >= 0)
      acc += ldw(cw, ow + (size_t)d * 4 + k, isbf) * bf2f(xzb[((size_t)(r + t - s) << 10) + d]);
  }
  xcb[idx] = f2bf(siluf(acc));
}

// ---------------- 3-phase scan: 4 n-states/thread; dBC is [rows][32] = B|C ----------
__global__ __launch_bounds__(256) void scan_p1_kernel(
    const u16* __restrict__ xcb, const u16* __restrict__ delb, const float* __restrict__ dBC,
    const float* __restrict__ Acp, int it, const int* __restrict__ pf,
    float* __restrict__ aggA, float* __restrict__ aggB)
{
  __shared__ float sb[32][16];   // B
  __shared__ u16 sdu[32][64];
  __shared__ u16 sxu[32][64];
  int tid = threadIdx.x;
  int di = tid >> 2, ng = tid & 3;
  int d0 = blockIdx.x << 6;
  int c = blockIdx.y, seq = blockIdx.z;
  int chain = seq >> 1, bb = seq & 1;
  int row0 = chain * 4096 + bb * S_LEN + c * CLEN;
  int i = chain * 2 + it;
  {
    int t = tid >> 3, e0 = (tid & 7) * 8;
    *(u16x8*)&sdu[t][e0] = *(const u16x8*)(delb + (size_t)(row0 + t) * 512 + d0 + e0);
    *(u16x8*)&sxu[t][e0] = *(const u16x8*)(xcb + (size_t)(row0 + t) * 512 + d0 + e0);
  }
  if (tid < 128) {
    int t = tid >> 2, e0 = (tid & 3) * 4;
    *(f32x4*)&sb[t][e0] = *(const f32x4*)(dBC + (size_t)(row0 + t) * 32 + e0);
  }
  f32x4 Ac = *(const f32x4*)(Acp + ((size_t)i * 512 + d0 + di) * 16 + ng * 4);
  __syncthreads();
  float h[4] = {0.f, 0.f, 0.f, 0.f};
  float ap[4] = {1.f, 1.f, 1.f, 1.f};
#pragma unroll 8
  for (int t = 0; t < CLEN; ++t) {
    float de = bf2f(sdu[t][di]);
    float dx = de * bf2f(sxu[t][di]);
    f32x4 B = *(const f32x4*)&sb[t][ng * 4];
#pragma unroll
    for (int j = 0; j < 4; ++j) {
      float e = __expf(de * Ac[j]);
      h[j] = e * h[j] + dx * B[j];
      ap[j] *= e;
    }
  }
  size_t o = (((size_t)(seq * NCHUNK + c) * DINNER) + d0 + di) * 16 + ng * 4;
  *(f32x4*)(aggA + o) = (f32x4){ap[0], ap[1], ap[2], ap[3]};
  *(f32x4*)(aggB + o) = (f32x4){h[0], h[1], h[2], h[3]};
}

__global__ __launch_bounds__(256) void scan_prefix_kernel(
    const float* __restrict__ aggA, float* __restrict__ aggB)
{
  int idx = blockIdx.x * 256 + threadIdx.x;   // 4*512*16
  int n = idx & 15, d = (idx >> 4) & 511, seq = idx >> 13;
  float h = 0.f;
  for (int c = 0; c < NCHUNK; ++c) {
    size_t o = (((size_t)(seq * NCHUNK + c) * DINNER) + d) * 16 + n;
    float a = aggA[o], t = aggB[o];
    aggB[o] = h;
    h = a * h + t;
  }
}

__global__ __launch_bounds__(256) void scan_p3_kernel(
    const u16* __restrict__ xcb, const u16* __restrict__ delb, const float* __restrict__ dBC,
    const u16* __restrict__ xzb, const float* __restrict__ hpref,
    const float* __restrict__ Acp, const void* __restrict__ Dp,
    int it, const int* __restrict__ pf, u16* __restrict__ ymb)
{
  const int isbf = *pf;
  __shared__ float sbc[32][32];  // B | C
  __shared__ float sy[32][64];
  __shared__ u16 sdu[32][64];
  __shared__ u16 sxu[32][64];
  __shared__ u16 szu[32][64];
  int tid = threadIdx.x;
  int di = tid >> 2, ng = tid & 3;
  int d0 = blockIdx.x << 6;
  int c = blockIdx.y, seq = blockIdx.z;
  int chain = seq >> 1, bb = seq & 1;
  int row0 = chain * 4096 + bb * S_LEN + c * CLEN;
  int i = chain * 2 + it;
  size_t oD = (size_t)i * 512;
  {
    int t = tid >> 3, e0 = (tid & 7) * 8;
    *(u16x8*)&sdu[t][e0] = *(const u16x8*)(delb + (size_t)(row0 + t) * 512 + d0 + e0);
    *(u16x8*)&sxu[t][e0] = *(const u16x8*)(xcb + (size_t)(row0 + t) * 512 + d0 + e0);
    *(u16x8*)&szu[t][e0] = *(const u16x8*)(xzb + ((size_t)(row0 + t) << 10) + 512 + d0 + e0);
  }
  {
    int t = tid >> 3, e0 = (tid & 7) * 4;
    *(f32x4*)&sbc[t][e0] = *(const f32x4*)(dBC + (size_t)(row0 + t) * 32 + e0);
  }
  f32x4 Ac = *(const f32x4*)(Acp + ((size_t)i * 512 + d0 + di) * 16 + ng * 4);
  float Dv = ldw(Dp, oD + d0 + di, isbf);
  float h[4];
  size_t o = (((size_t)(seq * NCHUNK + c) * DINNER) + d0 + di) * 16 + ng * 4;
  {
    f32x4 v = *(const f32x4*)(hpref + o);
    h[0] = v[0]; h[1] = v[1]; h[2] = v[2]; h[3] = v[3];
  }
  __syncthreads();
#pragma unroll 8
  for (int t = 0; t < CLEN; ++t) {
    float de = bf2f(sdu[t][di]);
    float xv = bf2f(sxu[t][di]);
    float dx = de * xv;
    f32x4 B = *(const f32x4*)&sbc[t][ng * 4];
    f32x4 C = *(const f32x4*)&sbc[t][16 + ng * 4];
    float yc = 0.f;
#pragma unroll
    for (int j = 0; j < 4; ++j) {
      float e = __expf(de * Ac[j]);
      h[j] = e * h[j] + dx * B[j];
      yc += h[j] * C[j];
    }
    yc += __shfl_xor(yc, 1, 64);
    yc += __shfl_xor(yc, 2, 64);
    if (ng == 0) sy[t][di] = yc + Dv * xv;
  }
  __syncthreads();
  int dcol = tid & 63;
#pragma unroll
  for (int k = 0; k < 8; ++k) {
    int t = (tid >> 6) + k * 4;
    float y = sy[t][dcol];
    float z = bf2f(szu[t][dcol]);
    ymb[(size_t)(row0 + t) * 512 + d0 + dcol] = f2bf(y * siluf(z));
  }
}

extern "C" void kernel_launch(void* const* d_in, const int* in_sizes, int n_in,
                              void* d_out, int out_size, void* d_ws, size_t ws_size,
                              hipStream_t stream)
{
  const void* x       = d_in[0];
  const void* in_w    = d_in[1];
  const void* conv_w  = d_in[2];
  const void* conv_b  = d_in[3];
  const void* A_log   = d_in[4];
  const void* xd_w    = d_in[5];
  const void* xB_w    = d_in[6];
  const void* xC_w    = d_in[7];
  const void* dtp_w   = d_in[8];
  const void* dtp_b   = d_in[9];
  const void* Dp      = d_in[10];
  const void* out_w   = d_in[11];
  const void* ln_g    = d_in[12];
  const void* ln_b    = d_in[13];
  const void* merge_w = d_in[14];

  // ---- workspace (~62.6 MB; proven-safe >= 65.5 MB) ----
  float* ws    = (float*)d_ws;
  float* res   = ws;                             // 8192x256 f32
  float* dBC   = res + (size_t)8192 * 256;       // 8192x32 f32 (B|C)
  float* aggA  = dBC + (size_t)8192 * 32;        // 2M f32 (xn & ym alias)
  float* aggB  = aggA + (size_t)2097152;         // 2M f32 (-> hpref)
  u16*   xz_bf = (u16*)(aggB + (size_t)2097152); // 8192x1024 (obA alias head)
  u16*   xc_bf = xz_bf + (size_t)8192 * 1024;    // 8192x512
  u16*   del_bf= xc_bf + (size_t)8192 * 512;     // 8192x512 (cat alias head)
  u16*   Wp_in = del_bf + (size_t)8192 * 512;    // 4*256*1024
  u16*   Wp_out= Wp_in + (size_t)4 * 262144;     // 4*512*256
  u16*   Wp_mg = Wp_out + (size_t)4 * 131072;    // 512*256
  u16*   Wp_cmb= Wp_mg + (size_t)131072;         // 4*512*576
  float* Acp   = (float*)(Wp_cmb + (size_t)4 * 294912);  // 4*512*16 f32
  int*   flagp = (int*)(Acp + (size_t)4 * 8192);
  u16*   obA_bf= xz_bf;          // alias
  u16*   xn_bf = (u16*)aggA;     // alias
  u16*   ym_bf = (u16*)aggA;     // alias
  u16*   cat_bf= del_bf;         // alias

  dim3 blk(256);
  hipLaunchKernelGGL(detect_kernel, dim3(1), blk, 0, stream, x, flagp);
  hipLaunchKernelGGL(apack_kernel, dim3(128), blk, 0, stream, A_log, flagp, Acp);
  hipLaunchKernelGGL(wpack_kernel, dim3(16, 8, 4), blk, 0, stream, in_w, flagp, Wp_in, 256, 1024);
  hipLaunchKernelGGL(wpack_kernel, dim3(4, 16, 4), blk, 0, stream, out_w, flagp, Wp_out, 512, 256);
  hipLaunchKernelGGL(wpack_kernel, dim3(4, 16, 1), blk, 0, stream, merge_w, flagp, Wp_mg, 512, 256);
  hipLaunchKernelGGL(wpack_cmb_kernel, dim3(9, 16, 4), blk, 0, stream,
      xd_w, dtp_w, xB_w, xC_w, flagp, Wp_cmb);

  for (int it = 0; it < 2; ++it) {
    hipLaunchKernelGGL(ln_kernel, dim3(8192), blk, 0, stream,
        x, obA_bf, it, ln_g, ln_b, flagp, res, xn_bf);
    hipLaunchKernelGGL((gemm64<2>), dim3(16, 128), blk, 0, stream,
        xn_bf, Wp_in, (size_t)it * 262144, (size_t)(2 + it) * 262144, 4096,
        (const float*)nullptr, (void*)xz_bf, (void*)nullptr,
        (const void*)nullptr, (size_t)0, (size_t)0, flagp, 1024, 256);
    hipLaunchKernelGGL(conv_kernel, dim3(16384), blk, 0, stream,
        xz_bf, conv_w, conv_b, it, flagp, xc_bf);
    hipLaunchKernelGGL((gemm64<5>), dim3(9, 128), blk, 0, stream,
        xc_bf, Wp_cmb, (size_t)it * 294912, (size_t)(2 + it) * 294912, 4096,
        (const float*)nullptr, (void*)del_bf, (void*)dBC,
        dtp_b, (size_t)it * 512, (size_t)(2 + it) * 512, flagp, 576, 512);
    hipLaunchKernelGGL(scan_p1_kernel, dim3(8, NCHUNK, 4), blk, 0, stream,
        xc_bf, del_bf, dBC, Acp, it, flagp, aggA, aggB);
    hipLaunchKernelGGL(scan_prefix_kernel, dim3(128), blk, 0, stream, aggA, aggB);
    hipLaunchKernelGGL(scan_p3_kernel, dim3(8, NCHUNK, 4), blk, 0, stream,
        xc_bf, del_bf, dBC, xz_bf, aggB, Acp, Dp, it, flagp, ym_bf);
    if (it == 0) {
      hipLaunchKernelGGL((gemm64<2>), dim3(4, 128), blk, 0, stream,
          ym_bf, Wp_out, (size_t)0, (size_t)2 * 131072, 4096,
          res, (void*)obA_bf, (void*)nullptr,
          (const void*)nullptr, (size_t)0, (size_t)0, flagp, 256, 512);
    } else {
      hipLaunchKernelGGL((gemm64<3>), dim3(4, 128), blk, 0, stream,
          ym_bf, Wp_out, (size_t)1 * 131072, (size_t)3 * 131072, 4096,
          res, (void*)cat_bf, (void*)nullptr,
          (const void*)nullptr, (size_t)0, (size_t)0, flagp, 256, 512);
    }
  }
  hipLaunchKernelGGL((gemm64<1>), dim3(4, 64), blk, 0, stream,
      cat_bf, Wp_mg, (size_t)0, (size_t)0, 0,
      (const float*)nullptr, d_out, (void*)nullptr,
      (const void*)nullptr, (size_t)0, (size_t)0, flagp, 256, 512);
}

// Round 17
// 395.576 us; speedup vs baseline: 1.1111x; 1.0209x over previous
//
#include <hip/hip_runtime.h>

#define S_LEN 2048
#define DINNER 512
#define NCHUNK 64
#define CLEN 32

typedef unsigned short u16;
typedef short bf16x8 __attribute__((ext_vector_type(8)));
typedef unsigned short u16x8 __attribute__((ext_vector_type(8)));  // 16 bytes
typedef float f32x4 __attribute__((ext_vector_type(4)));

__device__ __forceinline__ float bf2f(u16 u) {
  unsigned int x = ((unsigned int)u) << 16;
  float f; __builtin_memcpy(&f, &x, 4); return f;
}
__device__ __forceinline__ u16 f2bf(float f) {
  unsigned int x; __builtin_memcpy(&x, &f, 4);
  return (u16)((x + 0x7FFFu + ((x >> 16) & 1u)) >> 16);
}
__device__ __forceinline__ float ldw(const void* p, size_t i, int isbf) {
  return isbf ? bf2f(((const u16*)p)[i]) : ((const float*)p)[i];
}
__device__ __forceinline__ float siluf(float x) { return x / (1.f + __expf(-x)); }
__device__ __forceinline__ float softplusf(float x) {
  if (x > 20.f) return x;
  return log1pf(__expf(x));
}

// Detect input dtype (bf16 vs f32) from exponent-byte statistics.
__global__ __launch_bounds__(256) void detect_kernel(const void* __restrict__ x,
                                                     int* __restrict__ flag) {
  __shared__ int cnt;
  if (threadIdx.x == 0) cnt = 0;
  __syncthreads();
  u16 u = ((const u16*)x)[2 * threadIdx.x];
  int e = (u >> 7) & 0xFF;
  if (e >= 0x60 && e <= 0x8F) atomicAdd(&cnt, 1);
  __syncthreads();
  if (threadIdx.x == 0) *flag = (cnt > 128) ? 1 : 0;
}

// Precompute Acp[i][d][n] = -exp(A_log[i][d][n]) (f32, 4*512*16).
__global__ __launch_bounds__(256) void apack_kernel(
    const void* __restrict__ A_log, const int* __restrict__ pf, float* __restrict__ Acp)
{
  const int isbf = *pf;
  int idx = blockIdx.x * 256 + threadIdx.x;  // 32768
  Acp[idx] = -__expf(ldw(A_log, (size_t)idx, isbf));
}

// ---------------- weight pre-pack into MFMA fragment order ----------------
// Packed W[K][N]: chunk c = nblk16*(K/32) + kblk32, 512 bf16 per chunk;
// inside: q*128 + (n&15)*8 + (k&7).
__global__ __launch_bounds__(256) void wpack_kernel(
    const void* __restrict__ src, const int* __restrict__ pf,
    u16* __restrict__ dst, int K, int N)
{
  const int isbf = *pf;
  __shared__ float tile[32][65];
  int nb64 = blockIdx.x, kb = blockIdx.y, mat = blockIdx.z;
  size_t so = (size_t)mat * K * N;
  int tid = threadIdx.x;
  int kk = tid >> 3, nseg = (tid & 7) * 8;
#pragma unroll
  for (int j = 0; j < 8; ++j)
    tile[kk][nseg + j] = ldw(src, so + (size_t)(kb * 32 + kk) * N + nb64 * 64 + nseg + j, isbf);
  __syncthreads();
  int cc = tid >> 6, i0 = (tid & 63) * 8;
  int q = i0 >> 7, nn = (i0 >> 3) & 15;
  u16 outv[8];
#pragma unroll
  for (int j = 0; j < 8; ++j) outv[j] = f2bf(tile[q * 8 + j][cc * 16 + nn]);
  size_t doff = (size_t)mat * K * N + ((size_t)(nb64 * 4 + cc) * (K >> 5) + kb) * 512 + i0;
  *(u16x8*)(dst + doff) = *(const u16x8*)outv;
}

// Combined weight: [512 x 576] = [ xd_w@dtp_w (512) | xB_w (16) | xC_w (16) | 0 (32) ]
// packed to MFMA frag order. Grid (9 nb64, 16 kb, 4 mat).
__global__ __launch_bounds__(256) void wpack_cmb_kernel(
    const void* __restrict__ xdw, const void* __restrict__ dtpw,
    const void* __restrict__ xBw, const void* __restrict__ xCw,
    const int* __restrict__ pf, u16* __restrict__ dst)
{
  const int isbf = *pf;
  __shared__ float tile[32][65];
  int nb64 = blockIdx.x, kb = blockIdx.y, mat = blockIdx.z;
  int tid = threadIdx.x;
  if (nb64 < 8) {
    __shared__ float xd[32][33];
    __shared__ float wt[32][65];
    {
      int k = tid >> 3, j0 = (tid & 7) * 4;
#pragma unroll
      for (int j = 0; j < 4; ++j)
        xd[k][j0 + j] = ldw(xdw, (size_t)mat * 16384 + (size_t)(kb * 32 + k) * 32 + j0 + j, isbf);
      int jj = tid >> 3, n0l = (tid & 7) * 8;
#pragma unroll
      for (int n = 0; n < 8; ++n)
        wt[jj][n0l + n] = ldw(dtpw, (size_t)mat * 16384 + (size_t)jj * 512 + nb64 * 64 + n0l + n, isbf);
    }
    __syncthreads();
    for (int l = tid; l < 2048; l += 256) {
      int k = l >> 6, n = l & 63;
      float a = 0.f;
#pragma unroll
      for (int j = 0; j < 32; ++j) a += xd[k][j] * wt[j][n];
      tile[k][n] = a;
    }
  } else {
    for (int l = tid; l < 2048; l += 256) {
      int k = l >> 6, n = l & 63;
      int kg = kb * 32 + k;
      float v = 0.f;
      if (n < 16)      v = ldw(xBw, (size_t)mat * 8192 + (size_t)kg * 16 + n, isbf);
      else if (n < 32) v = ldw(xCw, (size_t)mat * 8192 + (size_t)kg * 16 + (n - 16), isbf);
      tile[k][n] = v;
    }
  }
  __syncthreads();
  int cc = tid >> 6, i0 = (tid & 63) * 8;
  int q = i0 >> 7, nn = (i0 >> 3) & 15;
  u16 outv[8];
#pragma unroll
  for (int j = 0; j < 8; ++j) outv[j] = f2bf(tile[q * 8 + j][cc * 16 + nn]);
  size_t doff = (size_t)mat * 294912 + ((size_t)(nb64 * 4 + cc) * 16 + kb) * 512 + i0;
  *(u16x8*)(dst + doff) = *(const u16x8*)outv;
}

// ---------------- LayerNorm (batched 2 chains) ----------------
__global__ __launch_bounds__(256) void ln_kernel(
    const void* __restrict__ x, const u16* __restrict__ obA, int it,
    const void* __restrict__ g, const void* __restrict__ bta,
    const int* __restrict__ pf, float* __restrict__ res, u16* __restrict__ xnb)
{
  const int isbf = *pf;
  int r = blockIdx.x;
  int tid = threadIdx.x;
  int chain = r >> 12, rr = r & 4095;
  int i = chain * 2 + it;
  size_t wo = (size_t)i * 256;
  float v;
  if (it == 0) {
    int b = rr >> 11, s = rr & 2047;
    int sr = chain ? (b * S_LEN + (S_LEN - 1 - s)) : rr;
    v = ldw(x, (size_t)sr * 256 + tid, isbf);
  } else {
    v = bf2f(obA[(size_t)r * 256 + tid]);
  }
  res[(size_t)r * 256 + tid] = v;
  float s1 = v, s2 = v * v;
#pragma unroll
  for (int o = 32; o > 0; o >>= 1) {
    s1 += __shfl_xor(s1, o, 64);
    s2 += __shfl_xor(s2, o, 64);
  }
  __shared__ float r1[4], r2[4];
  if ((tid & 63) == 0) { r1[tid >> 6] = s1; r2[tid >> 6] = s2; }
  __syncthreads();
  s1 = r1[0] + r1[1] + r1[2] + r1[3];
  s2 = r2[0] + r2[1] + r2[2] + r2[3];
  float mean = s1 * (1.f / 256.f);
  float var  = s2 * (1.f / 256.f) - mean * mean;
  float inv  = rsqrtf(var + 1e-5f);
  xnb[(size_t)r * 256 + tid] =
      f2bf((v - mean) * inv * ldw(g, wo + tid, isbf) + ldw(bta, wo + tid, isbf));
}

// ---------------- 4-wave MFMA GEMM: 64x64 tile, XCD-swizzled 1-D grid ----------------
// g = xcd + 8*(nIdx + nbx*mGrp): all n-blocks of one m-tile land on one XCD
// (round-robin heuristic) so A is fetched to that XCD's L2 once.
// OUTMODE 1: final dtype per flag. 2: bf16 [+res]. 3: cat buffer [+res].
// 5: cols<512 -> softplus(v+bias)->bf16 Out; cols 512-543 -> f32 Out2 (stride 32).
template<int OUTMODE>
__global__ __launch_bounds__(256) void gemm64(
    const u16* __restrict__ A, const u16* __restrict__ Wp, size_t woA, size_t woB, int mhalf,
    const float* __restrict__ res, void* __restrict__ Out, void* __restrict__ Out2,
    const void* __restrict__ bias, size_t boA, size_t boB,
    const int* __restrict__ pf, int N, int K, int nbx)
{
  const int isbf = *pf;
  __shared__ __align__(16) u16 Asb[64 * 32];
  __shared__ __align__(16) u16 Bsb[64 * 32];
  int tid = threadIdx.x;
  int gidx = blockIdx.x;
  int xcd = gidx & 7, rest = gidx >> 3;
  int nIdx = rest % nbx, mGrp = rest / nbx;
  int n0 = nIdx * 64, m0 = (xcd + (mGrp << 3)) * 64;
  size_t wo = (mhalf && m0 >= mhalf) ? woB : woA;
  int w = tid >> 6, lane = tid & 63;
  int q = lane >> 4, r = lane & 15;
  const int wm0 = (w >> 1) * 2, wn0 = (w & 1) * 2;
  const int kbs = K >> 5;
  f32x4 acc[2][2];
#pragma unroll
  for (int i = 0; i < 2; ++i)
#pragma unroll
    for (int j = 0; j < 2; ++j) acc[i][j] = (f32x4){0.f, 0.f, 0.f, 0.f};

  int sm = tid >> 2, sq = tid & 3;
  const u16* asrc = A + (size_t)(m0 + sm) * K + sq * 8;
  u16* adst = Asb + ((sm >> 4) * 4 + sq) * 128 + (sm & 15) * 8;
  int bnb = tid >> 6, binner = (tid & 63) * 8;
  u16* bdst = Bsb + bnb * 512 + binner;

  for (int k0 = 0; k0 < K; k0 += 32) {
    *(u16x8*)adst = *(const u16x8*)(asrc + k0);
    const u16* bsrc = Wp + wo + ((size_t)((n0 >> 4) + bnb) * kbs + (k0 >> 5)) * 512 + binner;
    *(u16x8*)bdst = *(const u16x8*)bsrc;
    __syncthreads();
    bf16x8 af[2], bfr[2];
#pragma unroll
    for (int i = 0; i < 2; ++i)
      af[i] = *(const bf16x8*)(Asb + ((wm0 + i) * 4 + q) * 128 + r * 8);
#pragma unroll
    for (int j = 0; j < 2; ++j)
      bfr[j] = *(const bf16x8*)(Bsb + ((wn0 + j) * 4 + q) * 128 + r * 8);
#pragma unroll
    for (int i = 0; i < 2; ++i)
#pragma unroll
      for (int j = 0; j < 2; ++j)
        acc[i][j] = __builtin_amdgcn_mfma_f32_16x16x32_bf16(af[i], bfr[j], acc[i][j], 0, 0, 0);
    __syncthreads();
  }
#pragma unroll
  for (int i = 0; i < 2; ++i) {
    int rowb = m0 + (wm0 + i) * 16 + q * 4;
#pragma unroll
    for (int j = 0; j < 2; ++j) {
      int col = n0 + (wn0 + j) * 16 + r;
#pragma unroll
      for (int t = 0; t < 4; ++t) {
        int row = rowb + t;
        float v = acc[i][j][t];
        if (OUTMODE == 2 || OUTMODE == 3) { if (res) v += res[(size_t)row * N + col]; }
        if (OUTMODE == 1) {
          size_t lidx = (size_t)row * N + col;
          if (isbf) ((u16*)Out)[lidx] = f2bf(v); else ((float*)Out)[lidx] = v;
        } else if (OUTMODE == 2) {
          ((u16*)Out)[(size_t)row * N + col] = f2bf(v);
        } else if (OUTMODE == 3) {
          int orow, cofx;
          if (row < 4096) { orow = row; cofx = 0; }
          else {
            int rr = row - 4096; int bb = rr >> 11, ss = rr & 2047;
            orow = bb * S_LEN + (S_LEN - 1 - ss); cofx = 256;
          }
          ((u16*)Out)[(size_t)orow * 512 + col + cofx] = f2bf(v);
        } else if (OUTMODE == 5) {
          if (col < 512) {
            float bv = ldw(bias, ((row < 4096) ? boA : boB) + col, isbf);
            ((u16*)Out)[(size_t)row * 512 + col] = f2bf(softplusf(v + bv));
          } else if (col < 544) {
            ((float*)Out2)[(size_t)row * 32 + (col - 512)] = v;
          }
        }
      }
    }
  }
}

// ---------------- causal depthwise conv K=4 + bias + SiLU, batched ----------------
__global__ __launch_bounds__(256) void conv_kernel(
    const u16* __restrict__ xzb, const void* __restrict__ cw, const void* __restrict__ cb,
    int it, const int* __restrict__ pf, u16* __restrict__ xcb)
{
  const int isbf = *pf;
  int idx = blockIdx.x * 256 + threadIdx.x;  // 8192*512
  int r = idx >> 9, d = idx & 511;
  int chain = r >> 12, rr = r & 4095;
  int i = chain * 2 + it;
  size_t ow = (size_t)i * 2048, ob = (size_t)i * 512;
  int s = rr & 2047;
  float acc = ldw(cb, ob + d, isbf);
#pragma unroll
  for (int k = 0; k < 4; ++k) {
    int t = s - 3 + k;
    if (t >= 0)
      acc += ldw(cw, ow + (size_t)d * 4 + k, isbf) * bf2f(xzb[((size_t)(r + t - s) << 10) + d]);
  }
  xcb[idx] = f2bf(siluf(acc));
}

// ---------------- 3-phase scan: 4 n-states/thread; dBC is [rows][32] = B|C ----------
__global__ __launch_bounds__(256) void scan_p1_kernel(
    const u16* __restrict__ xcb, const u16* __restrict__ delb, const float* __restrict__ dBC,
    const float* __restrict__ Acp, int it, const int* __restrict__ pf,
    float* __restrict__ aggA, float* __restrict__ aggB)
{
  __shared__ float sb[32][16];   // B
  __shared__ u16 sdu[32][64];
  __shared__ u16 sxu[32][64];
  int tid = threadIdx.x;
  int di = tid >> 2, ng = tid & 3;
  int d0 = blockIdx.x << 6;
  int c = blockIdx.y, seq = blockIdx.z;
  int chain = seq >> 1, bb = seq & 1;
  int row0 = chain * 4096 + bb * S_LEN + c * CLEN;
  int i = chain * 2 + it;
  {
    int t = tid >> 3, e0 = (tid & 7) * 8;
    *(u16x8*)&sdu[t][e0] = *(const u16x8*)(delb + (size_t)(row0 + t) * 512 + d0 + e0);
    *(u16x8*)&sxu[t][e0] = *(const u16x8*)(xcb + (size_t)(row0 + t) * 512 + d0 + e0);
  }
  if (tid < 128) {
    int t = tid >> 2, e0 = (tid & 3) * 4;
    *(f32x4*)&sb[t][e0] = *(const f32x4*)(dBC + (size_t)(row0 + t) * 32 + e0);
  }
  f32x4 Ac = *(const f32x4*)(Acp + ((size_t)i * 512 + d0 + di) * 16 + ng * 4);
  __syncthreads();
  float h[4] = {0.f, 0.f, 0.f, 0.f};
  float ap[4] = {1.f, 1.f, 1.f, 1.f};
#pragma unroll 8
  for (int t = 0; t < CLEN; ++t) {
    float de = bf2f(sdu[t][di]);
    float dx = de * bf2f(sxu[t][di]);
    f32x4 B = *(const f32x4*)&sb[t][ng * 4];
#pragma unroll
    for (int j = 0; j < 4; ++j) {
      float e = __expf(de * Ac[j]);
      h[j] = e * h[j] + dx * B[j];
      ap[j] *= e;
    }
  }
  size_t o = (((size_t)(seq * NCHUNK + c) * DINNER) + d0 + di) * 16 + ng * 4;
  *(f32x4*)(aggA + o) = (f32x4){ap[0], ap[1], ap[2], ap[3]};
  *(f32x4*)(aggB + o) = (f32x4){h[0], h[1], h[2], h[3]};
}

__global__ __launch_bounds__(256) void scan_prefix_kernel(
    const float* __restrict__ aggA, float* __restrict__ aggB)
{
  int idx = blockIdx.x * 256 + threadIdx.x;   // 4*512*16
  int n = idx & 15, d = (idx >> 4) & 511, seq = idx >> 13;
  float h = 0.f;
  for (int c = 0; c < NCHUNK; ++c) {
    size_t o = (((size_t)(seq * NCHUNK + c) * DINNER) + d) * 16 + n;
    float a = aggA[o], t = aggB[o];
    aggB[o] = h;
    h = a * h + t;
  }
}

__global__ __launch_bounds__(256) void scan_p3_kernel(
    const u16* __restrict__ xcb, const u16* __restrict__ delb, const float* __restrict__ dBC,
    const u16* __restrict__ xzb, const float* __restrict__ hpref,
    const float* __restrict__ Acp, const void* __restrict__ Dp,
    int it, const int* __restrict__ pf, u16* __restrict__ ymb)
{
  const int isbf = *pf;
  __shared__ float sbc[32][32];  // B | C
  __shared__ float sy[32][64];
  __shared__ u16 sdu[32][64];
  __shared__ u16 sxu[32][64];
  __shared__ u16 szu[32][64];
  int tid = threadIdx.x;
  int di = tid >> 2, ng = tid & 3;
  int d0 = blockIdx.x << 6;
  int c = blockIdx.y, seq = blockIdx.z;
  int chain = seq >> 1, bb = seq & 1;
  int row0 = chain * 4096 + bb * S_LEN + c * CLEN;
  int i = chain * 2 + it;
  size_t oD = (size_t)i * 512;
  {
    int t = tid >> 3, e0 = (tid & 7) * 8;
    *(u16x8*)&sdu[t][e0] = *(const u16x8*)(delb + (size_t)(row0 + t) * 512 + d0 + e0);
    *(u16x8*)&sxu[t][e0] = *(const u16x8*)(xcb + (size_t)(row0 + t) * 512 + d0 + e0);
    *(u16x8*)&szu[t][e0] = *(const u16x8*)(xzb + ((size_t)(row0 + t) << 10) + 512 + d0 + e0);
  }
  {
    int t = tid >> 3, e0 = (tid & 7) * 4;
    *(f32x4*)&sbc[t][e0] = *(const f32x4*)(dBC + (size_t)(row0 + t) * 32 + e0);
  }
  f32x4 Ac = *(const f32x4*)(Acp + ((size_t)i * 512 + d0 + di) * 16 + ng * 4);
  float Dv = ldw(Dp, oD + d0 + di, isbf);
  float h[4];
  size_t o = (((size_t)(seq * NCHUNK + c) * DINNER) + d0 + di) * 16 + ng * 4;
  {
    f32x4 v = *(const f32x4*)(hpref + o);
    h[0] = v[0]; h[1] = v[1]; h[2] = v[2]; h[3] = v[3];
  }
  __syncthreads();
#pragma unroll 8
  for (int t = 0; t < CLEN; ++t) {
    float de = bf2f(sdu[t][di]);
    float xv = bf2f(sxu[t][di]);
    float dx = de * xv;
    f32x4 B = *(const f32x4*)&sbc[t][ng * 4];
    f32x4 C = *(const f32x4*)&sbc[t][16 + ng * 4];
    float yc = 0.f;
#pragma unroll
    for (int j = 0; j < 4; ++j) {
      float e = __expf(de * Ac[j]);
      h[j] = e * h[j] + dx * B[j];
      yc += h[j] * C[j];
    }
    yc += __shfl_xor(yc, 1, 64);
    yc += __shfl_xor(yc, 2, 64);
    if (ng == 0) sy[t][di] = yc + Dv * xv;
  }
  __syncthreads();
  int dcol = tid & 63;
#pragma unroll
  for (int k = 0; k < 8; ++k) {
    int t = (tid >> 6) + k * 4;
    float y = sy[t][dcol];
    float z = bf2f(szu[t][dcol]);
    ymb[(size_t)(row0 + t) * 512 + d0 + dcol] = f2bf(y * siluf(z));
  }
}

extern "C" void kernel_launch(void* const* d_in, const int* in_sizes, int n_in,
                              void* d_out, int out_size, void* d_ws, size_t ws_size,
                              hipStream_t stream)
{
  const void* x       = d_in[0];
  const void* in_w    = d_in[1];
  const void* conv_w  = d_in[2];
  const void* conv_b  = d_in[3];
  const void* A_log   = d_in[4];
  const void* xd_w    = d_in[5];
  const void* xB_w    = d_in[6];
  const void* xC_w    = d_in[7];
  const void* dtp_w   = d_in[8];
  const void* dtp_b   = d_in[9];
  const void* Dp      = d_in[10];
  const void* out_w   = d_in[11];
  const void* ln_g    = d_in[12];
  const void* ln_b    = d_in[13];
  const void* merge_w = d_in[14];

  // ---- workspace (~62.6 MB; proven-safe >= 65.5 MB) ----
  float* ws    = (float*)d_ws;
  float* res   = ws;                             // 8192x256 f32
  float* dBC   = res + (size_t)8192 * 256;       // 8192x32 f32 (B|C)
  float* aggA  = dBC + (size_t)8192 * 32;        // 2M f32 (xn & ym alias)
  float* aggB  = aggA + (size_t)2097152;         // 2M f32 (-> hpref)
  u16*   xz_bf = (u16*)(aggB + (size_t)2097152); // 8192x1024 (obA alias head)
  u16*   xc_bf = xz_bf + (size_t)8192 * 1024;    // 8192x512
  u16*   del_bf= xc_bf + (size_t)8192 * 512;     // 8192x512 (cat alias head)
  u16*   Wp_in = del_bf + (size_t)8192 * 512;    // 4*256*1024
  u16*   Wp_out= Wp_in + (size_t)4 * 262144;     // 4*512*256
  u16*   Wp_mg = Wp_out + (size_t)4 * 131072;    // 512*256
  u16*   Wp_cmb= Wp_mg + (size_t)131072;         // 4*512*576
  float* Acp   = (float*)(Wp_cmb + (size_t)4 * 294912);  // 4*512*16 f32
  int*   flagp = (int*)(Acp + (size_t)4 * 8192);
  u16*   obA_bf= xz_bf;          // alias
  u16*   xn_bf = (u16*)aggA;     // alias
  u16*   ym_bf = (u16*)aggA;     // alias
  u16*   cat_bf= del_bf;         // alias

  dim3 blk(256);
  hipLaunchKernelGGL(detect_kernel, dim3(1), blk, 0, stream, x, flagp);
  hipLaunchKernelGGL(apack_kernel, dim3(128), blk, 0, stream, A_log, flagp, Acp);
  hipLaunchKernelGGL(wpack_kernel, dim3(16, 8, 4), blk, 0, stream, in_w, flagp, Wp_in, 256, 1024);
  hipLaunchKernelGGL(wpack_kernel, dim3(4, 16, 4), blk, 0, stream, out_w, flagp, Wp_out, 512, 256);
  hipLaunchKernelGGL(wpack_kernel, dim3(4, 16, 1), blk, 0, stream, merge_w, flagp, Wp_mg, 512, 256);
  hipLaunchKernelGGL(wpack_cmb_kernel, dim3(9, 16, 4), blk, 0, stream,
      xd_w, dtp_w, xB_w, xC_w, flagp, Wp_cmb);

  for (int it = 0; it < 2; ++it) {
    hipLaunchKernelGGL(ln_kernel, dim3(8192), blk, 0, stream,
        x, obA_bf, it, ln_g, ln_b, flagp, res, xn_bf);
    hipLaunchKernelGGL((gemm64<2>), dim3(16 * 128), blk, 0, stream,
        xn_bf, Wp_in, (size_t)it * 262144, (size_t)(2 + it) * 262144, 4096,
        (const float*)nullptr, (void*)xz_bf, (void*)nullptr,
        (const void*)nullptr, (size_t)0, (size_t)0, flagp, 1024, 256, 16);
    hipLaunchKernelGGL(conv_kernel, dim3(16384), blk, 0, stream,
        xz_bf, conv_w, conv_b, it, flagp, xc_bf);
    hipLaunchKernelGGL((gemm64<5>), dim3(9 * 128), blk, 0, stream,
        xc_bf, Wp_cmb, (size_t)it * 294912, (size_t)(2 + it) * 294912, 4096,
        (const float*)nullptr, (void*)del_bf, (void*)dBC,
        dtp_b, (size_t)it * 512, (size_t)(2 + it) * 512, flagp, 576, 512, 9);
    hipLaunchKernelGGL(scan_p1_kernel, dim3(8, NCHUNK, 4), blk, 0, stream,
        xc_bf, del_bf, dBC, Acp, it, flagp, aggA, aggB);
    hipLaunchKernelGGL(scan_prefix_kernel, dim3(128), blk, 0, stream, aggA, aggB);
    hipLaunchKernelGGL(scan_p3_kernel, dim3(8, NCHUNK, 4), blk, 0, stream,
        xc_bf, del_bf, dBC, xz_bf, aggB, Acp, Dp, it, flagp, ym_bf);
    if (it == 0) {
      hipLaunchKernelGGL((gemm64<2>), dim3(4 * 128), blk, 0, stream,
          ym_bf, Wp_out, (size_t)0, (size_t)2 * 131072, 4096,
          res, (void*)obA_bf, (void*)nullptr,
          (const void*)nullptr, (size_t)0, (size_t)0, flagp, 256, 512, 4);
    } else {
      hipLaunchKernelGGL((gemm64<3>), dim3(4 * 128), blk, 0, stream,
          ym_bf, Wp_out, (size_t)1 * 131072, (size_t)3 * 131072, 4096,
          res, (void*)cat_bf, (void*)nullptr,
          (const void*)nullptr, (size_t)0, (size_t)0, flagp, 256, 512, 4);
    }
  }
  hipLaunchKernelGGL((gemm64<1>), dim3(4 * 64), blk, 0, stream,
      cat_bf, Wp_mg, (size_t)0, (size_t)0, 0,
      (const float*)nullptr, d_out, (void*)nullptr,
      (const void*)nullptr, (size_t)0, (size_t)0, flagp, 256, 512, 4);
}

// Round 18
// 385.277 us; speedup vs baseline: 1.1408x; 1.0267x over previous
//
#include <hip/hip_runtime.h>

#define S_LEN 2048
#define DINNER 512
#define NCHUNK 64
#define CLEN 32

typedef unsigned short u16;
typedef short bf16x8 __attribute__((ext_vector_type(8)));
typedef unsigned short u16x8 __attribute__((ext_vector_type(8)));  // 16 bytes
typedef float f32x4 __attribute__((ext_vector_type(4)));

__device__ __forceinline__ float bf2f(u16 u) {
  unsigned int x = ((unsigned int)u) << 16;
  float f; __builtin_memcpy(&f, &x, 4); return f;
}
__device__ __forceinline__ u16 f2bf(float f) {
  unsigned int x; __builtin_memcpy(&x, &f, 4);
  return (u16)((x + 0x7FFFu + ((x >> 16) & 1u)) >> 16);
}
__device__ __forceinline__ float ldw(const void* p, size_t i, int isbf) {
  return isbf ? bf2f(((const u16*)p)[i]) : ((const float*)p)[i];
}
__device__ __forceinline__ float siluf(float x) { return x / (1.f + __expf(-x)); }
__device__ __forceinline__ float softplusf(float x) {
  if (x > 20.f) return x;
  return log1pf(__expf(x));
}

// Detect input dtype (bf16 vs f32) from exponent-byte statistics.
__global__ __launch_bounds__(256) void detect_kernel(const void* __restrict__ x,
                                                     int* __restrict__ flag) {
  __shared__ int cnt;
  if (threadIdx.x == 0) cnt = 0;
  __syncthreads();
  u16 u = ((const u16*)x)[2 * threadIdx.x];
  int e = (u >> 7) & 0xFF;
  if (e >= 0x60 && e <= 0x8F) atomicAdd(&cnt, 1);
  __syncthreads();
  if (threadIdx.x == 0) *flag = (cnt > 128) ? 1 : 0;
}

// Precompute Acp[i][d][n] = -exp(A_log[i][d][n]) (f32, 4*512*16).
__global__ __launch_bounds__(256) void apack_kernel(
    const void* __restrict__ A_log, const int* __restrict__ pf, float* __restrict__ Acp)
{
  const int isbf = *pf;
  int idx = blockIdx.x * 256 + threadIdx.x;  // 32768
  Acp[idx] = -__expf(ldw(A_log, (size_t)idx, isbf));
}

// ---------------- weight pre-pack into MFMA fragment order ----------------
// Packed W[K][N]: chunk c = nblk16*(K/32) + kblk32, 512 bf16 per chunk;
// inside: q*128 + (n&15)*8 + (k&7).
__global__ __launch_bounds__(256) void wpack_kernel(
    const void* __restrict__ src, const int* __restrict__ pf,
    u16* __restrict__ dst, int K, int N)
{
  const int isbf = *pf;
  __shared__ float tile[32][65];
  int nb64 = blockIdx.x, kb = blockIdx.y, mat = blockIdx.z;
  size_t so = (size_t)mat * K * N;
  int tid = threadIdx.x;
  int kk = tid >> 3, nseg = (tid & 7) * 8;
#pragma unroll
  for (int j = 0; j < 8; ++j)
    tile[kk][nseg + j] = ldw(src, so + (size_t)(kb * 32 + kk) * N + nb64 * 64 + nseg + j, isbf);
  __syncthreads();
  int cc = tid >> 6, i0 = (tid & 63) * 8;
  int q = i0 >> 7, nn = (i0 >> 3) & 15;
  u16 outv[8];
#pragma unroll
  for (int j = 0; j < 8; ++j) outv[j] = f2bf(tile[q * 8 + j][cc * 16 + nn]);
  size_t doff = (size_t)mat * K * N + ((size_t)(nb64 * 4 + cc) * (K >> 5) + kb) * 512 + i0;
  *(u16x8*)(dst + doff) = *(const u16x8*)outv;
}

// Combined weight: [512 x 576] = [ xd_w@dtp_w (512) | xB_w (16) | xC_w (16) | 0 (32) ]
// packed to MFMA frag order. Grid (9 nb64, 16 kb, 4 mat).
__global__ __launch_bounds__(256) void wpack_cmb_kernel(
    const void* __restrict__ xdw, const void* __restrict__ dtpw,
    const void* __restrict__ xBw, const void* __restrict__ xCw,
    const int* __restrict__ pf, u16* __restrict__ dst)
{
  const int isbf = *pf;
  __shared__ float tile[32][65];
  int nb64 = blockIdx.x, kb = blockIdx.y, mat = blockIdx.z;
  int tid = threadIdx.x;
  if (nb64 < 8) {
    __shared__ float xd[32][33];
    __shared__ float wt[32][65];
    {
      int k = tid >> 3, j0 = (tid & 7) * 4;
#pragma unroll
      for (int j = 0; j < 4; ++j)
        xd[k][j0 + j] = ldw(xdw, (size_t)mat * 16384 + (size_t)(kb * 32 + k) * 32 + j0 + j, isbf);
      int jj = tid >> 3, n0l = (tid & 7) * 8;
#pragma unroll
      for (int n = 0; n < 8; ++n)
        wt[jj][n0l + n] = ldw(dtpw, (size_t)mat * 16384 + (size_t)jj * 512 + nb64 * 64 + n0l + n, isbf);
    }
    __syncthreads();
    for (int l = tid; l < 2048; l += 256) {
      int k = l >> 6, n = l & 63;
      float a = 0.f;
#pragma unroll
      for (int j = 0; j < 32; ++j) a += xd[k][j] * wt[j][n];
      tile[k][n] = a;
    }
  } else {
    for (int l = tid; l < 2048; l += 256) {
      int k = l >> 6, n = l & 63;
      int kg = kb * 32 + k;
      float v = 0.f;
      if (n < 16)      v = ldw(xBw, (size_t)mat * 8192 + (size_t)kg * 16 + n, isbf);
      else if (n < 32) v = ldw(xCw, (size_t)mat * 8192 + (size_t)kg * 16 + (n - 16), isbf);
      tile[k][n] = v;
    }
  }
  __syncthreads();
  int cc = tid >> 6, i0 = (tid & 63) * 8;
  int q = i0 >> 7, nn = (i0 >> 3) & 15;
  u16 outv[8];
#pragma unroll
  for (int j = 0; j < 8; ++j) outv[j] = f2bf(tile[q * 8 + j][cc * 16 + nn]);
  size_t doff = (size_t)mat * 294912 + ((size_t)(nb64 * 4 + cc) * 16 + kb) * 512 + i0;
  *(u16x8*)(dst + doff) = *(const u16x8*)outv;
}

// ---------------- LayerNorm (batched 2 chains) ----------------
__global__ __launch_bounds__(256) void ln_kernel(
    const void* __restrict__ x, const u16* __restrict__ obA, int it,
    const void* __restrict__ g, const void* __restrict__ bta,
    const int* __restrict__ pf, float* __restrict__ res, u16* __restrict__ xnb)
{
  const int isbf = *pf;
  int r = blockIdx.x;
  int tid = threadIdx.x;
  int chain = r >> 12, rr = r & 4095;
  int i = chain * 2 + it;
  size_t wo = (size_t)i * 256;
  float v;
  if (it == 0) {
    int b = rr >> 11, s = rr & 2047;
    int sr = chain ? (b * S_LEN + (S_LEN - 1 - s)) : rr;
    v = ldw(x, (size_t)sr * 256 + tid, isbf);
  } else {
    v = bf2f(obA[(size_t)r * 256 + tid]);
  }
  res[(size_t)r * 256 + tid] = v;
  float s1 = v, s2 = v * v;
#pragma unroll
  for (int o = 32; o > 0; o >>= 1) {
    s1 += __shfl_xor(s1, o, 64);
    s2 += __shfl_xor(s2, o, 64);
  }
  __shared__ float r1[4], r2[4];
  if ((tid & 63) == 0) { r1[tid >> 6] = s1; r2[tid >> 6] = s2; }
  __syncthreads();
  s1 = r1[0] + r1[1] + r1[2] + r1[3];
  s2 = r2[0] + r2[1] + r2[2] + r2[3];
  float mean = s1 * (1.f / 256.f);
  float var  = s2 * (1.f / 256.f) - mean * mean;
  float inv  = rsqrtf(var + 1e-5f);
  xnb[(size_t)r * 256 + tid] =
      f2bf((v - mean) * inv * ldw(g, wo + tid, isbf) + ldw(bta, wo + tid, isbf));
}

// ---------------- 4-wave MFMA GEMM: 64x64 tile, BK=64, XCD-swizzled grid ----------
// Two 32-k chunks staged per barrier-pair (8 MFMA/wave per barrier).
// OUTMODE 1: final dtype per flag. 2: bf16 [+res]. 3: cat buffer [+res].
// 5: cols<512 -> softplus(v+bias)->bf16 Out; cols 512-543 -> f32 Out2 (stride 32).
template<int OUTMODE>
__global__ __launch_bounds__(256) void gemm64(
    const u16* __restrict__ A, const u16* __restrict__ Wp, size_t woA, size_t woB, int mhalf,
    const float* __restrict__ res, void* __restrict__ Out, void* __restrict__ Out2,
    const void* __restrict__ bias, size_t boA, size_t boB,
    const int* __restrict__ pf, int N, int K, int nbx)
{
  const int isbf = *pf;
  __shared__ __align__(16) u16 Asb[2 * 64 * 32];
  __shared__ __align__(16) u16 Bsb[2 * 64 * 32];
  int tid = threadIdx.x;
  int gidx = blockIdx.x;
  int xcd = gidx & 7, rest = gidx >> 3;
  int nIdx = rest % nbx, mGrp = rest / nbx;
  int n0 = nIdx * 64, m0 = (xcd + (mGrp << 3)) * 64;
  size_t wo = (mhalf && m0 >= mhalf) ? woB : woA;
  int w = tid >> 6, lane = tid & 63;
  int q = lane >> 4, r = lane & 15;
  const int wm0 = (w >> 1) * 2, wn0 = (w & 1) * 2;
  const int kbs = K >> 5;
  f32x4 acc[2][2];
#pragma unroll
  for (int i = 0; i < 2; ++i)
#pragma unroll
    for (int j = 0; j < 2; ++j) acc[i][j] = (f32x4){0.f, 0.f, 0.f, 0.f};

  int sm = tid >> 2, sq = tid & 3;
  const u16* asrc = A + (size_t)(m0 + sm) * K + sq * 8;
  u16* adst = Asb + ((sm >> 4) * 4 + sq) * 128 + (sm & 15) * 8;
  int bnb = tid >> 6, binner = (tid & 63) * 8;
  u16* bdst = Bsb + bnb * 512 + binner;

  for (int k0 = 0; k0 < K; k0 += 64) {
    *(u16x8*)adst          = *(const u16x8*)(asrc + k0);
    *(u16x8*)(adst + 2048) = *(const u16x8*)(asrc + k0 + 32);
    const u16* bsrc = Wp + wo + ((size_t)((n0 >> 4) + bnb) * kbs + (k0 >> 5)) * 512 + binner;
    *(u16x8*)bdst          = *(const u16x8*)bsrc;
    *(u16x8*)(bdst + 2048) = *(const u16x8*)(bsrc + 512);
    __syncthreads();
#pragma unroll
    for (int ck = 0; ck < 2; ++ck) {
      const u16* Ab = Asb + ck * 2048;
      const u16* Bb = Bsb + ck * 2048;
      bf16x8 af[2], bfr[2];
#pragma unroll
      for (int i = 0; i < 2; ++i)
        af[i] = *(const bf16x8*)(Ab + ((wm0 + i) * 4 + q) * 128 + r * 8);
#pragma unroll
      for (int j = 0; j < 2; ++j)
        bfr[j] = *(const bf16x8*)(Bb + ((wn0 + j) * 4 + q) * 128 + r * 8);
#pragma unroll
      for (int i = 0; i < 2; ++i)
#pragma unroll
        for (int j = 0; j < 2; ++j)
          acc[i][j] = __builtin_amdgcn_mfma_f32_16x16x32_bf16(af[i], bfr[j], acc[i][j], 0, 0, 0);
    }
    __syncthreads();
  }
#pragma unroll
  for (int i = 0; i < 2; ++i) {
    int rowb = m0 + (wm0 + i) * 16 + q * 4;
#pragma unroll
    for (int j = 0; j < 2; ++j) {
      int col = n0 + (wn0 + j) * 16 + r;
#pragma unroll
      for (int t = 0; t < 4; ++t) {
        int row = rowb + t;
        float v = acc[i][j][t];
        if (OUTMODE == 2 || OUTMODE == 3) { if (res) v += res[(size_t)row * N + col]; }
        if (OUTMODE == 1) {
          size_t lidx = (size_t)row * N + col;
          if (isbf) ((u16*)Out)[lidx] = f2bf(v); else ((float*)Out)[lidx] = v;
        } else if (OUTMODE == 2) {
          ((u16*)Out)[(size_t)row * N + col] = f2bf(v);
        } else if (OUTMODE == 3) {
          int orow, cofx;
          if (row < 4096) { orow = row; cofx = 0; }
          else {
            int rr = row - 4096; int bb = rr >> 11, ss = rr & 2047;
            orow = bb * S_LEN + (S_LEN - 1 - ss); cofx = 256;
          }
          ((u16*)Out)[(size_t)orow * 512 + col + cofx] = f2bf(v);
        } else if (OUTMODE == 5) {
          if (col < 512) {
            float bv = ldw(bias, ((row < 4096) ? boA : boB) + col, isbf);
            ((u16*)Out)[(size_t)row * 512 + col] = f2bf(softplusf(v + bv));
          } else if (col < 544) {
            ((float*)Out2)[(size_t)row * 32 + (col - 512)] = v;
          }
        }
      }
    }
  }
}

// ---------------- causal depthwise conv K=4 + bias + SiLU, batched ----------------
__global__ __launch_bounds__(256) void conv_kernel(
    const u16* __restrict__ xzb, const void* __restrict__ cw, const void* __restrict__ cb,
    int it, const int* __restrict__ pf, u16* __restrict__ xcb)
{
  const int isbf = *pf;
  int idx = blockIdx.x * 256 + threadIdx.x;  // 8192*512
  int r = idx >> 9, d = idx & 511;
  int chain = r >> 12, rr = r & 4095;
  int i = chain * 2 + it;
  size_t ow = (size_t)i * 2048, ob = (size_t)i * 512;
  int s = rr & 2047;
  float acc = ldw(cb, ob + d, isbf);
#pragma unroll
  for (int k = 0; k < 4; ++k) {
    int t = s - 3 + k;
    if (t >= 0)
      acc += ldw(cw, ow + (size_t)d * 4 + k, isbf) * bf2f(xzb[((size_t)(r + t - s) << 10) + d]);
  }
  xcb[idx] = f2bf(siluf(acc));
}

// ---------------- 3-phase scan: 4 n-states/thread; dBC is [rows][32] = B|C ----------
__global__ __launch_bounds__(256) void scan_p1_kernel(
    const u16* __restrict__ xcb, const u16* __restrict__ delb, const float* __restrict__ dBC,
    const float* __restrict__ Acp, int it, const int* __restrict__ pf,
    float* __restrict__ aggA, float* __restrict__ aggB)
{
  __shared__ float sb[32][16];   // B
  __shared__ u16 sdu[32][64];
  __shared__ u16 sxu[32][64];
  int tid = threadIdx.x;
  int di = tid >> 2, ng = tid & 3;
  int d0 = blockIdx.x << 6;
  int c = blockIdx.y, seq = blockIdx.z;
  int chain = seq >> 1, bb = seq & 1;
  int row0 = chain * 4096 + bb * S_LEN + c * CLEN;
  int i = chain * 2 + it;
  {
    int t = tid >> 3, e0 = (tid & 7) * 8;
    *(u16x8*)&sdu[t][e0] = *(const u16x8*)(delb + (size_t)(row0 + t) * 512 + d0 + e0);
    *(u16x8*)&sxu[t][e0] = *(const u16x8*)(xcb + (size_t)(row0 + t) * 512 + d0 + e0);
  }
  if (tid < 128) {
    int t = tid >> 2, e0 = (tid & 3) * 4;
    *(f32x4*)&sb[t][e0] = *(const f32x4*)(dBC + (size_t)(row0 + t) * 32 + e0);
  }
  f32x4 Ac = *(const f32x4*)(Acp + ((size_t)i * 512 + d0 + di) * 16 + ng * 4);
  __syncthreads();
  float h[4] = {0.f, 0.f, 0.f, 0.f};
  float ap[4] = {1.f, 1.f, 1.f, 1.f};
#pragma unroll 8
  for (int t = 0; t < CLEN; ++t) {
    float de = bf2f(sdu[t][di]);
    float dx = de * bf2f(sxu[t][di]);
    f32x4 B = *(const f32x4*)&sb[t][ng * 4];
#pragma unroll
    for (int j = 0; j < 4; ++j) {
      float e = __expf(de * Ac[j]);
      h[j] = e * h[j] + dx * B[j];
      ap[j] *= e;
    }
  }
  size_t o = (((size_t)(seq * NCHUNK + c) * DINNER) + d0 + di) * 16 + ng * 4;
  *(f32x4*)(aggA + o) = (f32x4){ap[0], ap[1], ap[2], ap[3]};
  *(f32x4*)(aggB + o) = (f32x4){h[0], h[1], h[2], h[3]};
}

__global__ __launch_bounds__(256) void scan_prefix_kernel(
    const float* __restrict__ aggA, float* __restrict__ aggB)
{
  int idx = blockIdx.x * 256 + threadIdx.x;   // 4*512*16
  int n = idx & 15, d = (idx >> 4) & 511, seq = idx >> 13;
  float h = 0.f;
  for (int c = 0; c < NCHUNK; ++c) {
    size_t o = (((size_t)(seq * NCHUNK + c) * DINNER) + d) * 16 + n;
    float a = aggA[o], t = aggB[o];
    aggB[o] = h;
    h = a * h + t;
  }
}

__global__ __launch_bounds__(256) void scan_p3_kernel(
    const u16* __restrict__ xcb, const u16* __restrict__ delb, const float* __restrict__ dBC,
    const u16* __restrict__ xzb, const float* __restrict__ hpref,
    const float* __restrict__ Acp, const void* __restrict__ Dp,
    int it, const int* __restrict__ pf, u16* __restrict__ ymb)
{
  const int isbf = *pf;
  __shared__ float sbc[32][32];  // B | C
  __shared__ float sy[32][64];
  __shared__ u16 sdu[32][64];
  __shared__ u16 sxu[32][64];
  __shared__ u16 szu[32][64];
  int tid = threadIdx.x;
  int di = tid >> 2, ng = tid & 3;
  int d0 = blockIdx.x << 6;
  int c = blockIdx.y, seq = blockIdx.z;
  int chain = seq >> 1, bb = seq & 1;
  int row0 = chain * 4096 + bb * S_LEN + c * CLEN;
  int i = chain * 2 + it;
  size_t oD = (size_t)i * 512;
  {
    int t = tid >> 3, e0 = (tid & 7) * 8;
    *(u16x8*)&sdu[t][e0] = *(const u16x8*)(delb + (size_t)(row0 + t) * 512 + d0 + e0);
    *(u16x8*)&sxu[t][e0] = *(const u16x8*)(xcb + (size_t)(row0 + t) * 512 + d0 + e0);
    *(u16x8*)&szu[t][e0] = *(const u16x8*)(xzb + ((size_t)(row0 + t) << 10) + 512 + d0 + e0);
  }
  {
    int t = tid >> 3, e0 = (tid & 7) * 4;
    *(f32x4*)&sbc[t][e0] = *(const f32x4*)(dBC + (size_t)(row0 + t) * 32 + e0);
  }
  f32x4 Ac = *(const f32x4*)(Acp + ((size_t)i * 512 + d0 + di) * 16 + ng * 4);
  float Dv = ldw(Dp, oD + d0 + di, isbf);
  float h[4];
  size_t o = (((size_t)(seq * NCHUNK + c) * DINNER) + d0 + di) * 16 + ng * 4;
  {
    f32x4 v = *(const f32x4*)(hpref + o);
    h[0] = v[0]; h[1] = v[1]; h[2] = v[2]; h[3] = v[3];
  }
  __syncthreads();
#pragma unroll 8
  for (int t = 0; t < CLEN; ++t) {
    float de = bf2f(sdu[t][di]);
    float xv = bf2f(sxu[t][di]);
    float dx = de * xv;
    f32x4 B = *(const f32x4*)&sbc[t][ng * 4];
    f32x4 C = *(const f32x4*)&sbc[t][16 + ng * 4];
    float yc = 0.f;
#pragma unroll
    for (int j = 0; j < 4; ++j) {
      float e = __expf(de * Ac[j]);
      h[j] = e * h[j] + dx * B[j];
      yc += h[j] * C[j];
    }
    yc += __shfl_xor(yc, 1, 64);
    yc += __shfl_xor(yc, 2, 64);
    if (ng == 0) sy[t][di] = yc + Dv * xv;
  }
  __syncthreads();
  int dcol = tid & 63;
#pragma unroll
  for (int k = 0; k < 8; ++k) {
    int t = (tid >> 6) + k * 4;
    float y = sy[t][dcol];
    float z = bf2f(szu[t][dcol]);
    ymb[(size_t)(row0 + t) * 512 + d0 + dcol] = f2bf(y * siluf(z));
  }
}

extern "C" void kernel_launch(void* const* d_in, const int* in_sizes, int n_in,
                              void* d_out, int out_size, void* d_ws, size_t ws_size,
                              hipStream_t stream)
{
  const void* x       = d_in[0];
  const void* in_w    = d_in[1];
  const void* conv_w  = d_in[2];
  const void* conv_b  = d_in[3];
  const void* A_log   = d_in[4];
  const void* xd_w    = d_in[5];
  const void* xB_w    = d_in[6];
  const void* xC_w    = d_in[7];
  const void* dtp_w   = d_in[8];
  const void* dtp_b   = d_in[9];
  const void* Dp      = d_in[10];
  const void* out_w   = d_in[11];
  const void* ln_g    = d_in[12];
  const void* ln_b    = d_in[13];
  const void* merge_w = d_in[14];

  // ---- workspace (~62.6 MB; proven-safe >= 65.5 MB) ----
  float* ws    = (float*)d_ws;
  float* res   = ws;                             // 8192x256 f32
  float* dBC   = res + (size_t)8192 * 256;       // 8192x32 f32 (B|C)
  float* aggA  = dBC + (size_t)8192 * 32;        // 2M f32 (xn & ym alias)
  float* aggB  = aggA + (size_t)2097152;         // 2M f32 (-> hpref)
  u16*   xz_bf = (u16*)(aggB + (size_t)2097152); // 8192x1024 (obA alias head)
  u16*   xc_bf = xz_bf + (size_t)8192 * 1024;    // 8192x512
  u16*   del_bf= xc_bf + (size_t)8192 * 512;     // 8192x512 (cat alias head)
  u16*   Wp_in = del_bf + (size_t)8192 * 512;    // 4*256*1024
  u16*   Wp_out= Wp_in + (size_t)4 * 262144;     // 4*512*256
  u16*   Wp_mg = Wp_out + (size_t)4 * 131072;    // 512*256
  u16*   Wp_cmb= Wp_mg + (size_t)131072;         // 4*512*576
  float* Acp   = (float*)(Wp_cmb + (size_t)4 * 294912);  // 4*512*16 f32
  int*   flagp = (int*)(Acp + (size_t)4 * 8192);
  u16*   obA_bf= xz_bf;          // alias
  u16*   xn_bf = (u16*)aggA;     // alias
  u16*   ym_bf = (u16*)aggA;     // alias
  u16*   cat_bf= del_bf;         // alias

  dim3 blk(256);
  hipLaunchKernelGGL(detect_kernel, dim3(1), blk, 0, stream, x, flagp);
  hipLaunchKernelGGL(apack_kernel, dim3(128), blk, 0, stream, A_log, flagp, Acp);
  hipLaunchKernelGGL(wpack_kernel, dim3(16, 8, 4), blk, 0, stream, in_w, flagp, Wp_in, 256, 1024);
  hipLaunchKernelGGL(wpack_kernel, dim3(4, 16, 4), blk, 0, stream, out_w, flagp, Wp_out, 512, 256);
  hipLaunchKernelGGL(wpack_kernel, dim3(4, 16, 1), blk, 0, stream, merge_w, flagp, Wp_mg, 512, 256);
  hipLaunchKernelGGL(wpack_cmb_kernel, dim3(9, 16, 4), blk, 0, stream,
      xd_w, dtp_w, xB_w, xC_w, flagp, Wp_cmb);

  for (int it = 0; it < 2; ++it) {
    hipLaunchKernelGGL(ln_kernel, dim3(8192), blk, 0, stream,
        x, obA_bf, it, ln_g, ln_b, flagp, res, xn_bf);
    hipLaunchKernelGGL((gemm64<2>), dim3(16 * 128), blk, 0, stream,
        xn_bf, Wp_in, (size_t)it * 262144, (size_t)(2 + it) * 262144, 4096,
        (const float*)nullptr, (void*)xz_bf, (void*)nullptr,
        (const void*)nullptr, (size_t)0, (size_t)0, flagp, 1024, 256, 16);
    hipLaunchKernelGGL(conv_kernel, dim3(16384), blk, 0, stream,
        xz_bf, conv_w, conv_b, it, flagp, xc_bf);
    hipLaunchKernelGGL((gemm64<5>), dim3(9 * 128), blk, 0, stream,
        xc_bf, Wp_cmb, (size_t)it * 294912, (size_t)(2 + it) * 294912, 4096,
        (const float*)nullptr, (void*)del_bf, (void*)dBC,
        dtp_b, (size_t)it * 512, (size_t)(2 + it) * 512, flagp, 576, 512, 9);
    hipLaunchKernelGGL(scan_p1_kernel, dim3(8, NCHUNK, 4), blk, 0, stream,
        xc_bf, del_bf, dBC, Acp, it, flagp, aggA, aggB);
    hipLaunchKernelGGL(scan_prefix_kernel, dim3(128), blk, 0, stream, aggA, aggB);
    hipLaunchKernelGGL(scan_p3_kernel, dim3(8, NCHUNK, 4), blk, 0, stream,
        xc_bf, del_bf, dBC, xz_bf, aggB, Acp, Dp, it, flagp, ym_bf);
    if (it == 0) {
      hipLaunchKernelGGL((gemm64<2>), dim3(4 * 128), blk, 0, stream,
          ym_bf, Wp_out, (size_t)0, (size_t)2 * 131072, 4096,
          res, (void*)obA_bf, (void*)nullptr,
          (const void*)nullptr, (size_t)0, (size_t)0, flagp, 256, 512, 4);
    } else {
      hipLaunchKernelGGL((gemm64<3>), dim3(4 * 128), blk, 0, stream,
          ym_bf, Wp_out, (size_t)1 * 131072, (size_t)3 * 131072, 4096,
          res, (void*)cat_bf, (void*)nullptr,
          (const void*)nullptr, (size_t)0, (size_t)0, flagp, 256, 512, 4);
    }
  }
  hipLaunchKernelGGL((gemm64<1>), dim3(4 * 64), blk, 0, stream,
      cat_bf, Wp_mg, (size_t)0, (size_t)0, 0,
      (const float*)nullptr, d_out, (void*)nullptr,
      (const void*)nullptr, (size_t)0, (size_t)0, flagp, 256, 512, 4);
}